// Round 1
// baseline (266.838 us; speedup 1.0000x reference)
//
#include <hip/hip_runtime.h>

#define DD 512
#define KM 5
#define B_ROWS 32768

typedef __attribute__((ext_vector_type(8))) short short8;
typedef __attribute__((ext_vector_type(4))) float f32x4;

static __device__ __forceinline__ short f2bf(float x) {
  unsigned u = __builtin_bit_cast(unsigned, x);
  u = (u + 0x7fffu + ((u >> 16) & 1u)) >> 16;
  return (short)u;
}
static __device__ __forceinline__ float bf2f(short s) {
  unsigned u = ((unsigned)(unsigned short)s) << 16;
  return __builtin_bit_cast(float, u);
}

// P[j][i] = sum_l X(j,l) * Y(i,l);  X(j,l) = XT ? X[l*DD+j] : X[j*DD+l]
template<bool XT>
__global__ __launch_bounds__(256)
void wprep(const float* __restrict__ X, const float* __restrict__ Y, short* __restrict__ P) {
  __shared__ float Xs[16][17];
  __shared__ float Ys[16][17];
  const int tx = threadIdx.x, ty = threadIdx.y;
  const int i0 = blockIdx.x * 16, j0 = blockIdx.y * 16;
  float acc = 0.f;
  for (int l0 = 0; l0 < DD; l0 += 16) {
    if (XT) {
      Xs[tx][ty] = X[(size_t)(l0 + ty) * DD + (j0 + tx)];
    } else {
      Xs[ty][tx] = X[(size_t)(j0 + ty) * DD + (l0 + tx)];
    }
    Ys[ty][tx] = Y[(size_t)(i0 + ty) * DD + (l0 + tx)];
    __syncthreads();
#pragma unroll
    for (int l = 0; l < 16; ++l) acc += Xs[ty][l] * Ys[tx][l];
    __syncthreads();
  }
  P[(size_t)(j0 + ty) * DD + (i0 + tx)] = f2bf(acc);
}

// block 0: w0[j] = sum_e bq[e]*Wk[j][e] ; block 1: d0[j] = sum_e bv[e]*Wo[e][j] + bo[j]
__global__ void biasprep(const float* __restrict__ bq, const float* __restrict__ Wk,
                         const float* __restrict__ bv, const float* __restrict__ Wo,
                         const float* __restrict__ bo, float* __restrict__ w0,
                         float* __restrict__ d0) {
  const int j = threadIdx.x;
  if (blockIdx.x == 0) {
    float s = 0.f;
    for (int e = 0; e < DD; ++e) s += bq[e] * Wk[(size_t)j * DD + e];
    w0[j] = s;
  } else {
    float s = 0.f;
    for (int e = 0; e < DD; ++e) s += bv[e] * Wo[(size_t)e * DD + j];
    d0[j] = s + bo[j];
  }
}

// out[b][j] = bf16( sum_i A[b][i] * Bt[j][i] + bias[j] )
// A: fp32 (AF32) or bf16 rows of length 512; Bt: bf16 [512][512] pre-transposed (n-major)
template<bool AF32>
__global__ __launch_bounds__(256)
void gemm_bt(const void* __restrict__ Ag, const short* __restrict__ Bt,
             const float* __restrict__ bias, short* __restrict__ outp) {
  __shared__ short As[128 * 32];
  __shared__ short Bs[128 * 32];
  const int tid  = threadIdx.x;
  const int lane = tid & 63;
  const int wave = tid >> 6;
  const int wr = wave >> 1, wc = wave & 1;
  const int bm = blockIdx.x, bn = blockIdx.y;
  const int kg = lane >> 4, lr = lane & 15;
  f32x4 acc[4][4] = {};
  for (int kt = 0; kt < DD; kt += 32) {
    {
      const short* src0 = Bt + (size_t)(bn * 128 + (tid >> 2)) * DD + kt + (tid & 3) * 8;
      __builtin_amdgcn_global_load_lds((const __attribute__((address_space(1))) void*)src0,
                                       (__attribute__((address_space(3))) void*)(Bs + wave * 512),
                                       16, 0, 0);
      const short* src1 = src0 + (size_t)64 * DD;
      __builtin_amdgcn_global_load_lds((const __attribute__((address_space(1))) void*)src1,
                                       (__attribute__((address_space(3))) void*)(Bs + 2048 + wave * 512),
                                       16, 0, 0);
    }
    if constexpr (AF32) {
      const float* Af = (const float*)Ag;
      const int row = tid >> 1, half = tid & 1;
      const float* src = Af + (size_t)(bm * 128 + row) * DD + kt + half * 16;
      f32x4 v0 = *(const f32x4*)(src + 0);
      f32x4 v1 = *(const f32x4*)(src + 4);
      f32x4 v2 = *(const f32x4*)(src + 8);
      f32x4 v3 = *(const f32x4*)(src + 12);
      short8 s0, s1;
      s0[0]=f2bf(v0[0]); s0[1]=f2bf(v0[1]); s0[2]=f2bf(v0[2]); s0[3]=f2bf(v0[3]);
      s0[4]=f2bf(v1[0]); s0[5]=f2bf(v1[1]); s0[6]=f2bf(v1[2]); s0[7]=f2bf(v1[3]);
      s1[0]=f2bf(v2[0]); s1[1]=f2bf(v2[1]); s1[2]=f2bf(v2[2]); s1[3]=f2bf(v2[3]);
      s1[4]=f2bf(v3[0]); s1[5]=f2bf(v3[1]); s1[6]=f2bf(v3[2]); s1[7]=f2bf(v3[3]);
      *(short8*)&As[row * 32 + half * 16 + 0] = s0;
      *(short8*)&As[row * 32 + half * 16 + 8] = s1;
    } else {
      const short* Ab = (const short*)Ag;
      const short* src0 = Ab + (size_t)(bm * 128 + (tid >> 2)) * DD + kt + (tid & 3) * 8;
      __builtin_amdgcn_global_load_lds((const __attribute__((address_space(1))) void*)src0,
                                       (__attribute__((address_space(3))) void*)(As + wave * 512),
                                       16, 0, 0);
      const short* src1 = src0 + (size_t)64 * DD;
      __builtin_amdgcn_global_load_lds((const __attribute__((address_space(1))) void*)src1,
                                       (__attribute__((address_space(3))) void*)(As + 2048 + wave * 512),
                                       16, 0, 0);
    }
    __syncthreads();
    short8 av[4], bv[4];
#pragma unroll
    for (int mi = 0; mi < 4; ++mi)
      av[mi] = *(const short8*)&As[(wr * 64 + mi * 16 + lr) * 32 + kg * 8];
#pragma unroll
    for (int ni = 0; ni < 4; ++ni)
      bv[ni] = *(const short8*)&Bs[(wc * 64 + ni * 16 + lr) * 32 + kg * 8];
#pragma unroll
    for (int mi = 0; mi < 4; ++mi)
#pragma unroll
      for (int ni = 0; ni < 4; ++ni)
        acc[mi][ni] = __builtin_amdgcn_mfma_f32_16x16x32_bf16(av[mi], bv[ni], acc[mi][ni], 0, 0, 0);
    __syncthreads();
  }
#pragma unroll
  for (int mi = 0; mi < 4; ++mi) {
#pragma unroll
    for (int ni = 0; ni < 4; ++ni) {
      const int col = bn * 128 + wc * 64 + ni * 16 + lr;
      const float bb = bias[col];
#pragma unroll
      for (int r = 0; r < 4; ++r) {
        const int row = bm * 128 + wr * 64 + mi * 16 + kg * 4 + r;
        outp[(size_t)row * DD + col] = f2bf(acc[mi][ni][r] + bb);
      }
    }
  }
}

// wave-per-row: scores = scale * t_b . M_bk ; masked softmax ; mbar = sum_k w_k M_bk
__global__ __launch_bounds__(256)
void attn_ws(const short* __restrict__ t, const float* __restrict__ mem,
             const int* __restrict__ mask, short* __restrict__ mbar) {
  const int b = blockIdx.x * 4 + (threadIdx.x >> 6);
  const int lane = threadIdx.x & 63;
  const short8 tv = *(const short8*)&t[(size_t)b * DD + lane * 8];
  float tf[8];
#pragma unroll
  for (int i = 0; i < 8; ++i) tf[i] = bf2f(tv[i]);
  float mk[KM][8];
  float s[KM];
#pragma unroll
  for (int k = 0; k < KM; ++k) {
    const float* mp = mem + ((size_t)b * KM + k) * DD + lane * 8;
    f32x4 a = *(const f32x4*)mp;
    f32x4 c = *(const f32x4*)(mp + 4);
    mk[k][0]=a[0]; mk[k][1]=a[1]; mk[k][2]=a[2]; mk[k][3]=a[3];
    mk[k][4]=c[0]; mk[k][5]=c[1]; mk[k][6]=c[2]; mk[k][7]=c[3];
    float p = 0.f;
#pragma unroll
    for (int i = 0; i < 8; ++i) p += tf[i] * mk[k][i];
    s[k] = p;
  }
#pragma unroll
  for (int k = 0; k < KM; ++k) {
#pragma unroll
    for (int off = 32; off > 0; off >>= 1) s[k] += __shfl_xor(s[k], off);
  }
  const float scale = 0.04419417382415922f;  // 512^-0.5
  bool valid[KM];
  float mx = -1e30f;
#pragma unroll
  for (int k = 0; k < KM; ++k) {
    valid[k] = mask[(size_t)b * KM + k] != 0;
    s[k] *= scale;
    if (valid[k]) mx = fmaxf(mx, s[k]);
  }
  float w[KM], sum = 0.f;
#pragma unroll
  for (int k = 0; k < KM; ++k) {
    w[k] = valid[k] ? __expf(s[k] - mx) : 0.f;
    sum += w[k];
  }
  const float inv = 1.f / sum;
  float o[8] = {0.f,0.f,0.f,0.f,0.f,0.f,0.f,0.f};
#pragma unroll
  for (int k = 0; k < KM; ++k) {
    const float wk = w[k] * inv;
#pragma unroll
    for (int i = 0; i < 8; ++i) o[i] += wk * mk[k][i];
  }
  short8 ov;
#pragma unroll
  for (int i = 0; i < 8; ++i) ov[i] = f2bf(o[i]);
  *(short8*)&mbar[(size_t)b * DD + lane * 8] = ov;
}

// out = LN(query + gate*conf*memO)
__global__ __launch_bounds__(256)
void fuse_ln(const float* __restrict__ query, const short* __restrict__ memO,
             const float* __restrict__ sims, const float* __restrict__ Wg,
             const float* __restrict__ bg, const float* __restrict__ ln_g,
             const float* __restrict__ ln_b, float* __restrict__ outp) {
  const int b = blockIdx.x * 4 + (threadIdx.x >> 6);
  const int lane = threadIdx.x & 63;
  const float* qp = query + (size_t)b * DD + lane * 8;
  f32x4 q0 = *(const f32x4*)qp;
  f32x4 q1 = *(const f32x4*)(qp + 4);
  float q[8] = {q0[0],q0[1],q0[2],q0[3],q1[0],q1[1],q1[2],q1[3]};
  const short8 mv = *(const short8*)&memO[(size_t)b * DD + lane * 8];
  float m[8];
#pragma unroll
  for (int i = 0; i < 8; ++i) m[i] = bf2f(mv[i]);
  const float* wg1 = Wg + lane * 8;
  const float* wg2 = Wg + DD + lane * 8;
  float gp = 0.f;
#pragma unroll
  for (int i = 0; i < 8; ++i) gp += q[i] * wg1[i] + m[i] * wg2[i];
#pragma unroll
  for (int off = 32; off > 0; off >>= 1) gp += __shfl_xor(gp, off);
  const float gate = 1.f / (1.f + __expf(-(gp + bg[0])));
  float ms = sims[(size_t)b * KM];
#pragma unroll
  for (int k = 1; k < KM; ++k) ms = fmaxf(ms, sims[(size_t)b * KM + k]);
  const float conf = 1.f / (1.f + __expf(-(ms - 0.7f)));  // GATE_TEMP=1.0, SIM_THRESH=0.7
  const float gc = gate * conf;
  float o[8];
  float s1 = 0.f, s2 = 0.f;
#pragma unroll
  for (int i = 0; i < 8; ++i) {
    o[i] = q[i] + gc * m[i];
    s1 += o[i];
    s2 += o[i] * o[i];
  }
#pragma unroll
  for (int off = 32; off > 0; off >>= 1) { s1 += __shfl_xor(s1, off); s2 += __shfl_xor(s2, off); }
  const float mu = s1 * (1.f / 512.f);
  const float var = s2 * (1.f / 512.f) - mu * mu;
  const float rs = rsqrtf(var + 1e-5f);
  const float* lg = ln_g + lane * 8;
  const float* lb = ln_b + lane * 8;
  f32x4 r0, r1;
#pragma unroll
  for (int i = 0; i < 4; ++i) r0[i] = (o[i] - mu) * rs * lg[i] + lb[i];
#pragma unroll
  for (int i = 0; i < 4; ++i) r1[i] = (o[4 + i] - mu) * rs * lg[4 + i] + lb[4 + i];
  float* op = outp + (size_t)b * DD + lane * 8;
  *(f32x4*)op = r0;
  *(f32x4*)(op + 4) = r1;
}

extern "C" void kernel_launch(void* const* d_in, const int* in_sizes, int n_in,
                              void* d_out, int out_size, void* d_ws, size_t ws_size,
                              hipStream_t stream) {
  const float* query = (const float*)d_in[0];
  const float* mem   = (const float*)d_in[1];
  const float* sims  = (const float*)d_in[2];
  const int*   mask  = (const int*)d_in[3];
  const float* Wq = (const float*)d_in[4];
  const float* bq = (const float*)d_in[5];
  const float* Wk = (const float*)d_in[6];
  // d_in[7] = bk: provably irrelevant (adds a per-row constant to scores; softmax shift-invariant)
  const float* Wv = (const float*)d_in[8];
  const float* bv = (const float*)d_in[9];
  const float* Wo = (const float*)d_in[10];
  const float* bo = (const float*)d_in[11];
  const float* Wg = (const float*)d_in[12];
  const float* bg = (const float*)d_in[13];
  const float* ln_g = (const float*)d_in[14];
  const float* ln_b = (const float*)d_in[15];
  float* out = (float*)d_out;

  // big bf16 intermediates live in d_out halves (t then m̄); memO + weights in ws
  short* t_buf  = (short*)d_out;                        // 32 MB (rows 0..B-1, bf16)
  short* mb_buf = (short*)d_out + (size_t)B_ROWS * DD;  // 32 MB
  char* ws = (char*)d_ws;
  short* mo_buf = (short*)ws;                           // 32 MB
  short* At = (short*)(ws + 33554432);                  // 512 KB  At[d][i] = (WqWk^T)[i][d]
  short* Ct = At + (size_t)DD * DD;                     // 512 KB  Ct[j][d] = (WvWo)[d][j]
  float* w0 = (float*)(Ct + (size_t)DD * DD);           // 2 KB
  float* d0 = w0 + DD;                                  // 2 KB

  dim3 wblk(16, 16), wgrd(32, 32);
  wprep<false><<<wgrd, wblk, 0, stream>>>(Wk, Wq, At);
  wprep<true ><<<wgrd, wblk, 0, stream>>>(Wo, Wv, Ct);
  biasprep<<<dim3(2), dim3(512), 0, stream>>>(bq, Wk, bv, Wo, bo, w0, d0);

  gemm_bt<true ><<<dim3(256, 4), dim3(256), 0, stream>>>((const void*)query, At, w0, t_buf);
  attn_ws<<<dim3(8192), dim3(256), 0, stream>>>(t_buf, mem, mask, mb_buf);
  gemm_bt<false><<<dim3(256, 4), dim3(256), 0, stream>>>((const void*)mb_buf, Ct, d0, mo_buf);
  fuse_ln<<<dim3(8192), dim3(256), 0, stream>>>(query, mo_buf, sims, Wg, bg, ln_g, ln_b, out);
}

// Round 3
// 217.180 us; speedup vs baseline: 1.2287x; 1.2287x over previous
//
#include <hip/hip_runtime.h>

#define DD 512
#define KM 5
#define B_ROWS 32768

typedef __attribute__((ext_vector_type(8))) short short8;
typedef __attribute__((ext_vector_type(4))) short s16x4;
typedef __attribute__((ext_vector_type(4))) float f32x4;

static __device__ __forceinline__ short f2bf(float x) {
  unsigned u = __builtin_bit_cast(unsigned, x);
  u = (u + 0x7fffu + ((u >> 16) & 1u)) >> 16;
  return (short)u;
}
static __device__ __forceinline__ float bf2f(short s) {
  unsigned u = ((unsigned)(unsigned short)s) << 16;
  return __builtin_bit_cast(float, u);
}

// P[j][i] = sum_l X(j,l) * Y(i,l);  X(j,l) = XT ? X[l*DD+j] : X[j*DD+l]
template<bool XT>
__global__ __launch_bounds__(256)
void wprep(const float* __restrict__ X, const float* __restrict__ Y, short* __restrict__ P) {
  __shared__ float Xs[16][17];
  __shared__ float Ys[16][17];
  const int tx = threadIdx.x, ty = threadIdx.y;
  const int i0 = blockIdx.x * 16, j0 = blockIdx.y * 16;
  float acc = 0.f;
  for (int l0 = 0; l0 < DD; l0 += 16) {
    if (XT) {
      Xs[tx][ty] = X[(size_t)(l0 + ty) * DD + (j0 + tx)];
    } else {
      Xs[ty][tx] = X[(size_t)(j0 + ty) * DD + (l0 + tx)];
    }
    Ys[ty][tx] = Y[(size_t)(i0 + ty) * DD + (l0 + tx)];
    __syncthreads();
#pragma unroll
    for (int l = 0; l < 16; ++l) acc += Xs[ty][l] * Ys[tx][l];
    __syncthreads();
  }
  P[(size_t)(j0 + ty) * DD + (i0 + tx)] = f2bf(acc);
}

// blocks 0..127: w0[j] = sum_e bq[e]*Wk[j][e]        (wave per j, row-coalesced)
// blocks 128..131: d0[j] = sum_e bv[e]*Wo[e][j] + bo (128 j per block, col-coalesced)
__global__ __launch_bounds__(256)
void biasprep2(const float* __restrict__ bq, const float* __restrict__ Wk,
               const float* __restrict__ bv, const float* __restrict__ Wo,
               const float* __restrict__ bo, float* __restrict__ w0,
               float* __restrict__ d0) {
  __shared__ float red[2][128];
  const int tid = threadIdx.x;
  if (blockIdx.x < 128) {
    const int j = blockIdx.x * 4 + (tid >> 6);
    const int lane = tid & 63;
    const float* r = Wk + (size_t)j * DD + lane * 8;
    f32x4 a = *(const f32x4*)r;
    f32x4 c = *(const f32x4*)(r + 4);
    const float* bp = bq + lane * 8;
    f32x4 ba = *(const f32x4*)bp;
    f32x4 bc = *(const f32x4*)(bp + 4);
    float s = a[0]*ba[0] + a[1]*ba[1] + a[2]*ba[2] + a[3]*ba[3]
            + c[0]*bc[0] + c[1]*bc[1] + c[2]*bc[2] + c[3]*bc[3];
#pragma unroll
    for (int off = 32; off > 0; off >>= 1) s += __shfl_xor(s, off);
    if (lane == 0) w0[j] = s;
  } else {
    const int j = (blockIdx.x - 128) * 128 + (tid & 127);
    const int half = tid >> 7;
    float s = 0.f;
    for (int e = half * 256; e < half * 256 + 256; ++e)
      s += bv[e] * Wo[(size_t)e * DD + j];
    red[half][tid & 127] = s;
    __syncthreads();
    if (half == 0) d0[j] = red[0][tid] + red[1][tid] + bo[j];
  }
}

// Megakernel 1: t = query@A + w0 (fp32 acc) -> masked softmax over scores -> mbar = sum_k w_k M
// Tile: 64 rows x 512 cols, 8 waves (wave w owns cols w*64..w*64+63). Grid = B/64 = 512.
__global__ __launch_bounds__(512, 1)
void mk1(const float* __restrict__ q, const short* __restrict__ Bt,
         const float* __restrict__ w0, const float* __restrict__ mem,
         const int* __restrict__ mask, short* __restrict__ mbar) {
  __shared__ short smem[32768];           // 64 KB
  short* As = smem;                       // [64][32]  (4 KB)
  short* Bs = smem + 2048;                // [512][32] (32 KB)
  const int tid = threadIdx.x;
  const int lane = tid & 63;
  const int w = tid >> 6;
  const int kg = lane >> 4, lr = lane & 15;
  const int bm = blockIdx.x;
  f32x4 acc[4][4] = {};
  for (int kt = 0; kt < DD; kt += 32) {
#pragma unroll
    for (int c = 0; c < 4; ++c) {
      const short* src = Bt + (size_t)(c * 128 + (tid >> 2)) * DD + kt + (tid & 3) * 8;
      __builtin_amdgcn_global_load_lds((const __attribute__((address_space(1))) void*)src,
                                       (__attribute__((address_space(3))) void*)(Bs + c * 4096 + w * 512),
                                       16, 0, 0);
    }
    {
      const float* s = q + (size_t)(bm * 64 + (tid >> 3)) * DD + kt + (tid & 7) * 4;
      f32x4 v = *(const f32x4*)s;
      s16x4 sv;
      sv[0] = f2bf(v[0]); sv[1] = f2bf(v[1]); sv[2] = f2bf(v[2]); sv[3] = f2bf(v[3]);
      *(s16x4*)&As[(tid >> 3) * 32 + (tid & 7) * 4] = sv;
    }
    __syncthreads();
    short8 av[4], bvv[4];
#pragma unroll
    for (int mi = 0; mi < 4; ++mi)
      av[mi] = *(const short8*)&As[(mi * 16 + lr) * 32 + kg * 8];
#pragma unroll
    for (int ni = 0; ni < 4; ++ni)
      bvv[ni] = *(const short8*)&Bs[(w * 64 + ni * 16 + lr) * 32 + kg * 8];
#pragma unroll
    for (int mi = 0; mi < 4; ++mi)
#pragma unroll
      for (int ni = 0; ni < 4; ++ni)
        acc[mi][ni] = __builtin_amdgcn_mfma_f32_16x16x32_bf16(av[mi], bvv[ni], acc[mi][ni], 0, 0, 0);
    __syncthreads();
  }
  // stage t (bf16) into full LDS: tls[64][512]
  short* tls = smem;
#pragma unroll
  for (int ni = 0; ni < 4; ++ni) {
    const int col = w * 64 + ni * 16 + lr;
    const float b0 = w0[col];
#pragma unroll
    for (int mi = 0; mi < 4; ++mi)
#pragma unroll
      for (int r = 0; r < 4; ++r)
        tls[(mi * 16 + kg * 4 + r) * DD + col] = f2bf(acc[mi][ni][r] + b0);
  }
  __syncthreads();
  // attention: wave w handles rows w*8 .. w*8+7
  const float scale = 0.044194173824159216f;  // 512^-0.5
  for (int rr = 0; rr < 8; ++rr) {
    const int row = w * 8 + rr;
    const size_t b = (size_t)bm * 64 + row;
    const short8 tv = *(const short8*)&tls[row * DD + lane * 8];
    float tf[8];
#pragma unroll
    for (int i = 0; i < 8; ++i) tf[i] = bf2f(tv[i]);
    float mkv[KM][8];
    float s[KM];
#pragma unroll
    for (int k = 0; k < KM; ++k) {
      const float* mp = mem + (b * KM + k) * DD + lane * 8;
      f32x4 a = *(const f32x4*)mp;
      f32x4 c = *(const f32x4*)(mp + 4);
      mkv[k][0]=a[0]; mkv[k][1]=a[1]; mkv[k][2]=a[2]; mkv[k][3]=a[3];
      mkv[k][4]=c[0]; mkv[k][5]=c[1]; mkv[k][6]=c[2]; mkv[k][7]=c[3];
      float p = 0.f;
#pragma unroll
      for (int i = 0; i < 8; ++i) p += tf[i] * mkv[k][i];
      s[k] = p;
    }
#pragma unroll
    for (int k = 0; k < KM; ++k) {
#pragma unroll
      for (int off = 32; off > 0; off >>= 1) s[k] += __shfl_xor(s[k], off);
    }
    float mx = -1e30f;
    bool valid[KM];
#pragma unroll
    for (int k = 0; k < KM; ++k) {
      valid[k] = mask[b * KM + k] != 0;
      s[k] *= scale;
      if (valid[k]) mx = fmaxf(mx, s[k]);
    }
    float wk[KM], sum = 0.f;
#pragma unroll
    for (int k = 0; k < KM; ++k) {
      wk[k] = valid[k] ? __expf(s[k] - mx) : 0.f;
      sum += wk[k];
    }
    const float inv = 1.f / sum;
    float o[8] = {0.f,0.f,0.f,0.f,0.f,0.f,0.f,0.f};
#pragma unroll
    for (int k = 0; k < KM; ++k) {
      const float g = wk[k] * inv;
#pragma unroll
      for (int i = 0; i < 8; ++i) o[i] += g * mkv[k][i];
    }
    short8 ov;
#pragma unroll
    for (int i = 0; i < 8; ++i) ov[i] = f2bf(o[i]);
    *(short8*)&mbar[b * DD + lane * 8] = ov;
  }
}

// Megakernel 2: memO = mbar@C + d0 (fp32 acc) -> gate/conf -> residual -> LayerNorm -> out
__global__ __launch_bounds__(512, 1)
void mk2(const short* __restrict__ mb, const short* __restrict__ Ct,
         const float* __restrict__ d0, const float* __restrict__ q,
         const float* __restrict__ sims, const float* __restrict__ Wg,
         const float* __restrict__ bg, const float* __restrict__ lng,
         const float* __restrict__ lnb, float* __restrict__ outp) {
  __shared__ short smem[32768];
  short* As = smem;
  short* Bs = smem + 2048;
  const int tid = threadIdx.x;
  const int lane = tid & 63;
  const int w = tid >> 6;
  const int kg = lane >> 4, lr = lane & 15;
  const int bm = blockIdx.x;
  f32x4 acc[4][4] = {};
  for (int kt = 0; kt < DD; kt += 32) {
#pragma unroll
    for (int c = 0; c < 4; ++c) {
      const short* src = Ct + (size_t)(c * 128 + (tid >> 2)) * DD + kt + (tid & 3) * 8;
      __builtin_amdgcn_global_load_lds((const __attribute__((address_space(1))) void*)src,
                                       (__attribute__((address_space(3))) void*)(Bs + c * 4096 + w * 512),
                                       16, 0, 0);
    }
    if (w < 4) {
      const short* src = mb + (size_t)(bm * 64 + (tid >> 2)) * DD + kt + (tid & 3) * 8;
      __builtin_amdgcn_global_load_lds((const __attribute__((address_space(1))) void*)src,
                                       (__attribute__((address_space(3))) void*)(As + w * 512),
                                       16, 0, 0);
    }
    __syncthreads();
    short8 av[4], bvv[4];
#pragma unroll
    for (int mi = 0; mi < 4; ++mi)
      av[mi] = *(const short8*)&As[(mi * 16 + lr) * 32 + kg * 8];
#pragma unroll
    for (int ni = 0; ni < 4; ++ni)
      bvv[ni] = *(const short8*)&Bs[(w * 64 + ni * 16 + lr) * 32 + kg * 8];
#pragma unroll
    for (int mi = 0; mi < 4; ++mi)
#pragma unroll
      for (int ni = 0; ni < 4; ++ni)
        acc[mi][ni] = __builtin_amdgcn_mfma_f32_16x16x32_bf16(av[mi], bvv[ni], acc[mi][ni], 0, 0, 0);
    __syncthreads();
  }
  // stage memO (bf16) into LDS: mls[64][512]
  short* mls = smem;
#pragma unroll
  for (int ni = 0; ni < 4; ++ni) {
    const int col = w * 64 + ni * 16 + lr;
    const float b0 = d0[col];
#pragma unroll
    for (int mi = 0; mi < 4; ++mi)
#pragma unroll
      for (int r = 0; r < 4; ++r)
        mls[(mi * 16 + kg * 4 + r) * DD + col] = f2bf(acc[mi][ni][r] + b0);
  }
  __syncthreads();
  // fusion + LN: wave w handles rows w*8 .. w*8+7
  const float* wg1 = Wg + lane * 8;
  const float* wg2 = Wg + DD + lane * 8;
  f32x4 g1a = *(const f32x4*)wg1, g1b = *(const f32x4*)(wg1 + 4);
  f32x4 g2a = *(const f32x4*)wg2, g2b = *(const f32x4*)(wg2 + 4);
  f32x4 la = *(const f32x4*)(lng + lane * 8), lb4 = *(const f32x4*)(lng + lane * 8 + 4);
  f32x4 ba = *(const f32x4*)(lnb + lane * 8), bb4 = *(const f32x4*)(lnb + lane * 8 + 4);
  const float bgs = bg[0];
  for (int rr = 0; rr < 8; ++rr) {
    const int row = w * 8 + rr;
    const size_t b = (size_t)bm * 64 + row;
    const float* qp = q + b * DD + lane * 8;
    f32x4 q0 = *(const f32x4*)qp;
    f32x4 q1 = *(const f32x4*)(qp + 4);
    float qf[8] = {q0[0],q0[1],q0[2],q0[3],q1[0],q1[1],q1[2],q1[3]};
    const short8 mv = *(const short8*)&mls[row * DD + lane * 8];
    float mf[8];
#pragma unroll
    for (int i = 0; i < 8; ++i) mf[i] = bf2f(mv[i]);
    float gp = qf[0]*g1a[0]+qf[1]*g1a[1]+qf[2]*g1a[2]+qf[3]*g1a[3]
             + qf[4]*g1b[0]+qf[5]*g1b[1]+qf[6]*g1b[2]+qf[7]*g1b[3]
             + mf[0]*g2a[0]+mf[1]*g2a[1]+mf[2]*g2a[2]+mf[3]*g2a[3]
             + mf[4]*g2b[0]+mf[5]*g2b[1]+mf[6]*g2b[2]+mf[7]*g2b[3];
#pragma unroll
    for (int off = 32; off > 0; off >>= 1) gp += __shfl_xor(gp, off);
    const float gate = 1.f / (1.f + __expf(-(gp + bgs)));
    float ms = sims[b * KM];
#pragma unroll
    for (int k = 1; k < KM; ++k) ms = fmaxf(ms, sims[b * KM + k]);
    const float conf = 1.f / (1.f + __expf(-(ms - 0.7f)));
    const float gc = gate * conf;
    float o[8];
    float s1 = 0.f, s2 = 0.f;
#pragma unroll
    for (int i = 0; i < 8; ++i) {
      o[i] = qf[i] + gc * mf[i];
      s1 += o[i];
      s2 += o[i] * o[i];
    }
#pragma unroll
    for (int off = 32; off > 0; off >>= 1) { s1 += __shfl_xor(s1, off); s2 += __shfl_xor(s2, off); }
    const float mu = s1 * (1.f / 512.f);
    const float var = s2 * (1.f / 512.f) - mu * mu;
    const float rs = rsqrtf(var + 1e-5f);
    f32x4 r0, r1;
#pragma unroll
    for (int i = 0; i < 4; ++i) r0[i] = (o[i] - mu) * rs * la[i] + ba[i];
#pragma unroll
    for (int i = 0; i < 4; ++i) r1[i] = (o[4 + i] - mu) * rs * lb4[i] + bb4[i];
    float* op = outp + b * DD + lane * 8;
    *(f32x4*)op = r0;
    *(f32x4*)(op + 4) = r1;
  }
}

extern "C" void kernel_launch(void* const* d_in, const int* in_sizes, int n_in,
                              void* d_out, int out_size, void* d_ws, size_t ws_size,
                              hipStream_t stream) {
  const float* query = (const float*)d_in[0];
  const float* mem   = (const float*)d_in[1];
  const float* sims  = (const float*)d_in[2];
  const int*   mask  = (const int*)d_in[3];
  const float* Wq = (const float*)d_in[4];
  const float* bq = (const float*)d_in[5];
  const float* Wk = (const float*)d_in[6];
  // d_in[7] = bk: irrelevant (per-row constant on scores; softmax shift-invariant)
  const float* Wv = (const float*)d_in[8];
  const float* bv = (const float*)d_in[9];
  const float* Wo = (const float*)d_in[10];
  const float* bo = (const float*)d_in[11];
  const float* Wg = (const float*)d_in[12];
  const float* bg = (const float*)d_in[13];
  const float* ln_g = (const float*)d_in[14];
  const float* ln_b = (const float*)d_in[15];
  float* out = (float*)d_out;

  char* ws = (char*)d_ws;
  short* mb = (short*)ws;                               // 32 MB  (mbar, bf16)
  short* At = (short*)(ws + 33554432);                  // 512 KB  At[j][i] = (WqWk^T)[i][j] (n-major)
  short* Ct = At + (size_t)DD * DD;                     // 512 KB  Ct[j][d] = (WvWo)[d][j]
  float* w0 = (float*)(Ct + (size_t)DD * DD);           // 2 KB
  float* d0 = w0 + DD;                                  // 2 KB

  dim3 wblk(16, 16), wgrd(32, 32);
  wprep<false><<<wgrd, wblk, 0, stream>>>(Wk, Wq, At);
  wprep<true ><<<wgrd, wblk, 0, stream>>>(Wo, Wv, Ct);
  biasprep2<<<dim3(132), dim3(256), 0, stream>>>(bq, Wk, bv, Wo, bo, w0, d0);

  mk1<<<dim3(B_ROWS / 64), dim3(512), 0, stream>>>(query, At, w0, mem, mask, mb);
  mk2<<<dim3(B_ROWS / 64), dim3(512), 0, stream>>>(mb, Ct, d0, query, sims, Wg, bg, ln_g, ln_b, out);
}

// Round 4
// 188.749 us; speedup vs baseline: 1.4137x; 1.1506x over previous
//
#include <hip/hip_runtime.h>

#define DD 512
#define KM 5
#define B_ROWS 32768

typedef __attribute__((ext_vector_type(8))) short short8;
typedef __attribute__((ext_vector_type(4))) short s16x4;
typedef __attribute__((ext_vector_type(4))) float f32x4;

static __device__ __forceinline__ short f2bf(float x) {
  unsigned u = __builtin_bit_cast(unsigned, x);
  u = (u + 0x7fffu + ((u >> 16) & 1u)) >> 16;
  return (short)u;
}
static __device__ __forceinline__ float bf2f(short s) {
  unsigned u = ((unsigned)(unsigned short)s) << 16;
  return __builtin_bit_cast(float, u);
}

// P[j][i] = sum_l X(j,l) * Y(i,l);  X(j,l) = XT ? X[l*DD+j] : X[j*DD+l]
template<bool XT>
__global__ __launch_bounds__(256)
void wprep(const float* __restrict__ X, const float* __restrict__ Y, short* __restrict__ P) {
  __shared__ float Xs[16][17];
  __shared__ float Ys[16][17];
  const int tx = threadIdx.x, ty = threadIdx.y;
  const int i0 = blockIdx.x * 16, j0 = blockIdx.y * 16;
  float acc = 0.f;
  for (int l0 = 0; l0 < DD; l0 += 16) {
    if (XT) {
      Xs[tx][ty] = X[(size_t)(l0 + ty) * DD + (j0 + tx)];
    } else {
      Xs[ty][tx] = X[(size_t)(j0 + ty) * DD + (l0 + tx)];
    }
    Ys[ty][tx] = Y[(size_t)(i0 + ty) * DD + (l0 + tx)];
    __syncthreads();
#pragma unroll
    for (int l = 0; l < 16; ++l) acc += Xs[ty][l] * Ys[tx][l];
    __syncthreads();
  }
  P[(size_t)(j0 + ty) * DD + (i0 + tx)] = f2bf(acc);
}

// blocks 0..127: w0[j] = sum_e bq[e]*Wk[j][e]        (wave per j, row-coalesced)
// blocks 128..131: d0[j] = sum_e bv[e]*Wo[e][j] + bo (128 j per block, col-coalesced)
__global__ __launch_bounds__(256)
void biasprep2(const float* __restrict__ bq, const float* __restrict__ Wk,
               const float* __restrict__ bv, const float* __restrict__ Wo,
               const float* __restrict__ bo, float* __restrict__ w0,
               float* __restrict__ d0) {
  __shared__ float red[2][128];
  const int tid = threadIdx.x;
  if (blockIdx.x < 128) {
    const int j = blockIdx.x * 4 + (tid >> 6);
    const int lane = tid & 63;
    const float* r = Wk + (size_t)j * DD + lane * 8;
    f32x4 a = *(const f32x4*)r;
    f32x4 c = *(const f32x4*)(r + 4);
    const float* bp = bq + lane * 8;
    f32x4 ba = *(const f32x4*)bp;
    f32x4 bc = *(const f32x4*)(bp + 4);
    float s = a[0]*ba[0] + a[1]*ba[1] + a[2]*ba[2] + a[3]*ba[3]
            + c[0]*bc[0] + c[1]*bc[1] + c[2]*bc[2] + c[3]*bc[3];
#pragma unroll
    for (int off = 32; off > 0; off >>= 1) s += __shfl_xor(s, off);
    if (lane == 0) w0[j] = s;
  } else {
    const int j = (blockIdx.x - 128) * 128 + (tid & 127);
    const int half = tid >> 7;
    float s = 0.f;
    for (int e = half * 256; e < half * 256 + 256; ++e)
      s += bv[e] * Wo[(size_t)e * DD + j];
    red[half][tid & 127] = s;
    __syncthreads();
    if (half == 0) d0[j] = red[0][tid] + red[1][tid] + bo[j];
  }
}

// per-row softmax + weighted-sum finisher (static indexing via macro; VM is scalar mask bits)
#define ROW_FINISH(SV, MA, MC, VM, BIDX)                                    \
    {                                                                       \
      float mx = -1e30f;                                                    \
      _Pragma("unroll") for (int k = 0; k < KM; ++k)                        \
        if ((VM) & (1 << k)) mx = fmaxf(mx, SV[k]);                         \
      float wk[KM]; float sum = 0.f;                                        \
      _Pragma("unroll") for (int k = 0; k < KM; ++k) {                      \
        wk[k] = ((VM) & (1 << k)) ? __expf(SV[k] - mx) : 0.f;               \
        sum += wk[k];                                                       \
      }                                                                     \
      const float inv = 1.f / sum;                                          \
      float o[8] = {0.f,0.f,0.f,0.f,0.f,0.f,0.f,0.f};                       \
      _Pragma("unroll") for (int k = 0; k < KM; ++k)                        \
        if ((VM) & (1 << k)) {                                              \
          const float g = wk[k] * inv;                                      \
          _Pragma("unroll") for (int i = 0; i < 4; ++i) {                   \
            o[i] += g * MA[k][i]; o[4 + i] += g * MC[k][i];                 \
          }                                                                 \
        }                                                                   \
      short8 ov;                                                            \
      _Pragma("unroll") for (int i = 0; i < 8; ++i) ov[i] = f2bf(o[i]);     \
      *(short8*)&mbar[(BIDX) * DD + lane * 8] = ov;                         \
    }

// Megakernel 1: t = query@A + w0 (fp32 acc) -> masked softmax (skip invalid mem rows)
//               -> mbar = sum_k w_k M.  64 rows x 512 cols, 8 waves. Grid = B/64.
__global__ __launch_bounds__(512, 3)
void mk1(const float* __restrict__ q, const short* __restrict__ Bt,
         const float* __restrict__ w0, const float* __restrict__ mem,
         const int* __restrict__ mask, short* __restrict__ mbar) {
  __shared__ short smem[32768];           // 64 KB
  short* As = smem;                       // [64][32]  (4 KB)
  short* Bs = smem + 2048;                // [512][32] (32 KB)
  const int tid = threadIdx.x;
  const int lane = tid & 63;
  const int w = tid >> 6;
  const int kg = lane >> 4, lr = lane & 15;
  const int bm = blockIdx.x;
  f32x4 acc[4][4] = {};
  // A-prefetch registers (fp32 q slice for current k-tile)
  const int arow = tid >> 3, acol = (tid & 7) * 4;
  const float* qbase = q + (size_t)(bm * 64 + arow) * DD + acol;
  f32x4 qv = *(const f32x4*)qbase;
  for (int kt = 0; kt < DD; kt += 32) {
#pragma unroll
    for (int c = 0; c < 4; ++c) {
      const short* src = Bt + (size_t)(c * 128 + (tid >> 2)) * DD + kt + (tid & 3) * 8;
      __builtin_amdgcn_global_load_lds((const __attribute__((address_space(1))) void*)src,
                                       (__attribute__((address_space(3))) void*)(Bs + c * 4096 + w * 512),
                                       16, 0, 0);
    }
    {
      s16x4 sv;
      sv[0] = f2bf(qv[0]); sv[1] = f2bf(qv[1]); sv[2] = f2bf(qv[2]); sv[3] = f2bf(qv[3]);
      *(s16x4*)&As[arow * 32 + acol] = sv;
    }
    __syncthreads();
    // prefetch next k-tile's q slice; waits land at next iteration's use, hidden under MFMA
    f32x4 qnext = {};
    if (kt + 32 < DD) qnext = *(const f32x4*)(qbase + kt + 32);
    short8 av[4], bvv[4];
#pragma unroll
    for (int mi = 0; mi < 4; ++mi)
      av[mi] = *(const short8*)&As[(mi * 16 + lr) * 32 + kg * 8];
#pragma unroll
    for (int ni = 0; ni < 4; ++ni)
      bvv[ni] = *(const short8*)&Bs[(w * 64 + ni * 16 + lr) * 32 + kg * 8];
#pragma unroll
    for (int mi = 0; mi < 4; ++mi)
#pragma unroll
      for (int ni = 0; ni < 4; ++ni)
        acc[mi][ni] = __builtin_amdgcn_mfma_f32_16x16x32_bf16(av[mi], bvv[ni], acc[mi][ni], 0, 0, 0);
    __syncthreads();
    qv = qnext;
  }
  // stage t (bf16) into full LDS: tls[64][512]
  short* tls = smem;
#pragma unroll
  for (int ni = 0; ni < 4; ++ni) {
    const int col = w * 64 + ni * 16 + lr;
    const float b0 = w0[col];
#pragma unroll
    for (int mi = 0; mi < 4; ++mi)
#pragma unroll
      for (int r = 0; r < 4; ++r)
        tls[(mi * 16 + kg * 4 + r) * DD + col] = f2bf(acc[mi][ni][r] + b0);
  }
  __syncthreads();
  // attention: wave w handles rows w*8 .. w*8+7, two rows per iteration.
  const float scale = 0.044194173824159216f;  // 512^-0.5
  for (int rr = 0; rr < 8; rr += 2) {
    const int row0 = w * 8 + rr;
    const size_t b0 = (size_t)bm * 64 + row0;
    const short8 tv0 = *(const short8*)&tls[row0 * DD + lane * 8];
    const short8 tv1 = *(const short8*)&tls[(row0 + 1) * DD + lane * 8];
    float tf0[8], tf1[8];
#pragma unroll
    for (int i = 0; i < 8; ++i) { tf0[i] = bf2f(tv0[i]); tf1[i] = bf2f(tv1[i]); }
    // scalar (wave-uniform) validity bits -> skip invalid mem rows entirely
    int vm0 = 0, vm1 = 0;
#pragma unroll
    for (int k = 0; k < KM; ++k) {
      vm0 |= (__builtin_amdgcn_readfirstlane(mask[b0 * KM + k]) ? 1 : 0) << k;
      vm1 |= (__builtin_amdgcn_readfirstlane(mask[(b0 + 1) * KM + k]) ? 1 : 0) << k;
    }
    f32x4 ma0[KM], mc0[KM], ma1[KM], mc1[KM];
#pragma unroll
    for (int k = 0; k < KM; ++k) {
      if (vm0 & (1 << k)) {
        const f32x4* mp = (const f32x4*)(mem + (b0 * KM + k) * DD + lane * 8);
        ma0[k] = __builtin_nontemporal_load(mp);
        mc0[k] = __builtin_nontemporal_load(mp + 1);
      }
      if (vm1 & (1 << k)) {
        const f32x4* mp = (const f32x4*)(mem + ((b0 + 1) * KM + k) * DD + lane * 8);
        ma1[k] = __builtin_nontemporal_load(mp);
        mc1[k] = __builtin_nontemporal_load(mp + 1);
      }
    }
    float s0[KM], s1[KM];
#pragma unroll
    for (int k = 0; k < KM; ++k) {
      if (vm0 & (1 << k)) {
        float p = 0.f;
#pragma unroll
        for (int i = 0; i < 4; ++i) { p += tf0[i] * ma0[k][i]; p += tf0[4 + i] * mc0[k][i]; }
#pragma unroll
        for (int off = 32; off > 0; off >>= 1) p += __shfl_xor(p, off);
        s0[k] = p * scale;
      }
      if (vm1 & (1 << k)) {
        float p = 0.f;
#pragma unroll
        for (int i = 0; i < 4; ++i) { p += tf1[i] * ma1[k][i]; p += tf1[4 + i] * mc1[k][i]; }
#pragma unroll
        for (int off = 32; off > 0; off >>= 1) p += __shfl_xor(p, off);
        s1[k] = p * scale;
      }
    }
    ROW_FINISH(s0, ma0, mc0, vm0, b0)
    ROW_FINISH(s1, ma1, mc1, vm1, (b0 + 1))
  }
}

// Megakernel 2: memO = mbar@C + d0 (fp32 acc) -> gate/conf -> residual -> LayerNorm -> out
__global__ __launch_bounds__(512, 1)
void mk2(const short* __restrict__ mb, const short* __restrict__ Ct,
         const float* __restrict__ d0, const float* __restrict__ q,
         const float* __restrict__ sims, const float* __restrict__ Wg,
         const float* __restrict__ bg, const float* __restrict__ lng,
         const float* __restrict__ lnb, float* __restrict__ outp) {
  __shared__ short smem[32768];
  short* As = smem;
  short* Bs = smem + 2048;
  const int tid = threadIdx.x;
  const int lane = tid & 63;
  const int w = tid >> 6;
  const int kg = lane >> 4, lr = lane & 15;
  const int bm = blockIdx.x;
  f32x4 acc[4][4] = {};
  for (int kt = 0; kt < DD; kt += 32) {
#pragma unroll
    for (int c = 0; c < 4; ++c) {
      const short* src = Ct + (size_t)(c * 128 + (tid >> 2)) * DD + kt + (tid & 3) * 8;
      __builtin_amdgcn_global_load_lds((const __attribute__((address_space(1))) void*)src,
                                       (__attribute__((address_space(3))) void*)(Bs + c * 4096 + w * 512),
                                       16, 0, 0);
    }
    if (w < 4) {
      const short* src = mb + (size_t)(bm * 64 + (tid >> 2)) * DD + kt + (tid & 3) * 8;
      __builtin_amdgcn_global_load_lds((const __attribute__((address_space(1))) void*)src,
                                       (__attribute__((address_space(3))) void*)(As + w * 512),
                                       16, 0, 0);
    }
    __syncthreads();
    short8 av[4], bvv[4];
#pragma unroll
    for (int mi = 0; mi < 4; ++mi)
      av[mi] = *(const short8*)&As[(mi * 16 + lr) * 32 + kg * 8];
#pragma unroll
    for (int ni = 0; ni < 4; ++ni)
      bvv[ni] = *(const short8*)&Bs[(w * 64 + ni * 16 + lr) * 32 + kg * 8];
#pragma unroll
    for (int mi = 0; mi < 4; ++mi)
#pragma unroll
      for (int ni = 0; ni < 4; ++ni)
        acc[mi][ni] = __builtin_amdgcn_mfma_f32_16x16x32_bf16(av[mi], bvv[ni], acc[mi][ni], 0, 0, 0);
    __syncthreads();
  }
  // stage memO (bf16) into LDS: mls[64][512]
  short* mls = smem;
#pragma unroll
  for (int ni = 0; ni < 4; ++ni) {
    const int col = w * 64 + ni * 16 + lr;
    const float b0 = d0[col];
#pragma unroll
    for (int mi = 0; mi < 4; ++mi)
#pragma unroll
      for (int r = 0; r < 4; ++r)
        mls[(mi * 16 + kg * 4 + r) * DD + col] = f2bf(acc[mi][ni][r] + b0);
  }
  __syncthreads();
  // fusion + LN: wave w handles rows w*8 .. w*8+7
  const float* wg1 = Wg + lane * 8;
  const float* wg2 = Wg + DD + lane * 8;
  f32x4 g1a = *(const f32x4*)wg1, g1b = *(const f32x4*)(wg1 + 4);
  f32x4 g2a = *(const f32x4*)wg2, g2b = *(const f32x4*)(wg2 + 4);
  f32x4 la = *(const f32x4*)(lng + lane * 8), lb4 = *(const f32x4*)(lng + lane * 8 + 4);
  f32x4 ba = *(const f32x4*)(lnb + lane * 8), bb4 = *(const f32x4*)(lnb + lane * 8 + 4);
  const float bgs = bg[0];
  for (int rr = 0; rr < 8; ++rr) {
    const int row = w * 8 + rr;
    const size_t b = (size_t)bm * 64 + row;
    const float* qp = q + b * DD + lane * 8;
    f32x4 q0 = *(const f32x4*)qp;
    f32x4 q1 = *(const f32x4*)(qp + 4);
    float qf[8] = {q0[0],q0[1],q0[2],q0[3],q1[0],q1[1],q1[2],q1[3]};
    const short8 mv = *(const short8*)&mls[row * DD + lane * 8];
    float mf[8];
#pragma unroll
    for (int i = 0; i < 8; ++i) mf[i] = bf2f(mv[i]);
    float gp = qf[0]*g1a[0]+qf[1]*g1a[1]+qf[2]*g1a[2]+qf[3]*g1a[3]
             + qf[4]*g1b[0]+qf[5]*g1b[1]+qf[6]*g1b[2]+qf[7]*g1b[3]
             + mf[0]*g2a[0]+mf[1]*g2a[1]+mf[2]*g2a[2]+mf[3]*g2a[3]
             + mf[4]*g2b[0]+mf[5]*g2b[1]+mf[6]*g2b[2]+mf[7]*g2b[3];
#pragma unroll
    for (int off = 32; off > 0; off >>= 1) gp += __shfl_xor(gp, off);
    const float gate = 1.f / (1.f + __expf(-(gp + bgs)));
    float ms = sims[b * KM];
#pragma unroll
    for (int k = 1; k < KM; ++k) ms = fmaxf(ms, sims[b * KM + k]);
    const float conf = 1.f / (1.f + __expf(-(ms - 0.7f)));
    const float gc = gate * conf;
    float o[8];
    float s1 = 0.f, s2 = 0.f;
#pragma unroll
    for (int i = 0; i < 8; ++i) {
      o[i] = qf[i] + gc * mf[i];
      s1 += o[i];
      s2 += o[i] * o[i];
    }
#pragma unroll
    for (int off = 32; off > 0; off >>= 1) { s1 += __shfl_xor(s1, off); s2 += __shfl_xor(s2, off); }
    const float mu = s1 * (1.f / 512.f);
    const float var = s2 * (1.f / 512.f) - mu * mu;
    const float rs = rsqrtf(var + 1e-5f);
    f32x4 r0, r1;
#pragma unroll
    for (int i = 0; i < 4; ++i) r0[i] = (o[i] - mu) * rs * la[i] + ba[i];
#pragma unroll
    for (int i = 0; i < 4; ++i) r1[i] = (o[4 + i] - mu) * rs * lb4[i] + bb4[i];
    float* op = outp + b * DD + lane * 8;
    *(f32x4*)op = r0;
    *(f32x4*)(op + 4) = r1;
  }
}

extern "C" void kernel_launch(void* const* d_in, const int* in_sizes, int n_in,
                              void* d_out, int out_size, void* d_ws, size_t ws_size,
                              hipStream_t stream) {
  const float* query = (const float*)d_in[0];
  const float* mem   = (const float*)d_in[1];
  const float* sims  = (const float*)d_in[2];
  const int*   mask  = (const int*)d_in[3];
  const float* Wq = (const float*)d_in[4];
  const float* bq = (const float*)d_in[5];
  const float* Wk = (const float*)d_in[6];
  // d_in[7] = bk: irrelevant (per-row constant on scores; softmax shift-invariant)
  const float* Wv = (const float*)d_in[8];
  const float* bv = (const float*)d_in[9];
  const float* Wo = (const float*)d_in[10];
  const float* bo = (const float*)d_in[11];
  const float* Wg = (const float*)d_in[12];
  const float* bg = (const float*)d_in[13];
  const float* ln_g = (const float*)d_in[14];
  const float* ln_b = (const float*)d_in[15];
  float* out = (float*)d_out;

  char* ws = (char*)d_ws;
  short* mb = (short*)ws;                               // 32 MB  (mbar, bf16)
  short* At = (short*)(ws + 33554432);                  // 512 KB  At[j][i] = (WqWk^T)[i][j] (n-major)
  short* Ct = At + (size_t)DD * DD;                     // 512 KB  Ct[j][d] = (WvWo)[d][j]
  float* w0 = (float*)(Ct + (size_t)DD * DD);           // 2 KB
  float* d0 = w0 + DD;                                  // 2 KB

  dim3 wblk(16, 16), wgrd(32, 32);
  wprep<false><<<wgrd, wblk, 0, stream>>>(Wk, Wq, At);
  wprep<true ><<<wgrd, wblk, 0, stream>>>(Wo, Wv, Ct);
  biasprep2<<<dim3(132), dim3(256), 0, stream>>>(bq, Wk, bv, Wo, bo, w0, d0);

  mk1<<<dim3(B_ROWS / 64), dim3(512), 0, stream>>>(query, At, w0, mem, mask, mb);
  mk2<<<dim3(B_ROWS / 64), dim3(512), 0, stream>>>(mb, Ct, d0, query, sims, Wg, bg, ln_g, ln_b, out);
}

// Round 5
// 182.742 us; speedup vs baseline: 1.4602x; 1.0329x over previous
//
#include <hip/hip_runtime.h>

#define DD 512
#define KM 5
#define B_ROWS 32768

typedef __attribute__((ext_vector_type(8))) short short8;
typedef __attribute__((ext_vector_type(4))) short s16x4;
typedef __attribute__((ext_vector_type(4))) float f32x4;

static __device__ __forceinline__ short f2bf(float x) {
  unsigned u = __builtin_bit_cast(unsigned, x);
  u = (u + 0x7fffu + ((u >> 16) & 1u)) >> 16;
  return (short)u;
}
static __device__ __forceinline__ float bf2f(short s) {
  unsigned u = ((unsigned)(unsigned short)s) << 16;
  return __builtin_bit_cast(float, u);
}

// P[j][i] = sum_l X(j,l) * Y(i,l);  X(j,l) = XT ? X[l*DD+j] : X[j*DD+l]
template<bool XT>
__global__ __launch_bounds__(256)
void wprep(const float* __restrict__ X, const float* __restrict__ Y, short* __restrict__ P) {
  __shared__ float Xs[16][17];
  __shared__ float Ys[16][17];
  const int tx = threadIdx.x, ty = threadIdx.y;
  const int i0 = blockIdx.x * 16, j0 = blockIdx.y * 16;
  float acc = 0.f;
  for (int l0 = 0; l0 < DD; l0 += 16) {
    if (XT) {
      Xs[tx][ty] = X[(size_t)(l0 + ty) * DD + (j0 + tx)];
    } else {
      Xs[ty][tx] = X[(size_t)(j0 + ty) * DD + (l0 + tx)];
    }
    Ys[ty][tx] = Y[(size_t)(i0 + ty) * DD + (l0 + tx)];
    __syncthreads();
#pragma unroll
    for (int l = 0; l < 16; ++l) acc += Xs[ty][l] * Ys[tx][l];
    __syncthreads();
  }
  P[(size_t)(j0 + ty) * DD + (i0 + tx)] = f2bf(acc);
}

// blocks 0..127: w0[j] = sum_e bq[e]*Wk[j][e]        (wave per j, row-coalesced)
// blocks 128..131: d0[j] = sum_e bv[e]*Wo[e][j] + bo (128 j per block, col-coalesced)
__global__ __launch_bounds__(256)
void biasprep2(const float* __restrict__ bq, const float* __restrict__ Wk,
               const float* __restrict__ bv, const float* __restrict__ Wo,
               const float* __restrict__ bo, float* __restrict__ w0,
               float* __restrict__ d0) {
  __shared__ float red[2][128];
  const int tid = threadIdx.x;
  if (blockIdx.x < 128) {
    const int j = blockIdx.x * 4 + (tid >> 6);
    const int lane = tid & 63;
    const float* r = Wk + (size_t)j * DD + lane * 8;
    f32x4 a = *(const f32x4*)r;
    f32x4 c = *(const f32x4*)(r + 4);
    const float* bp = bq + lane * 8;
    f32x4 ba = *(const f32x4*)bp;
    f32x4 bc = *(const f32x4*)(bp + 4);
    float s = a[0]*ba[0] + a[1]*ba[1] + a[2]*ba[2] + a[3]*ba[3]
            + c[0]*bc[0] + c[1]*bc[1] + c[2]*bc[2] + c[3]*bc[3];
#pragma unroll
    for (int off = 32; off > 0; off >>= 1) s += __shfl_xor(s, off);
    if (lane == 0) w0[j] = s;
  } else {
    const int j = (blockIdx.x - 128) * 128 + (tid & 127);
    const int half = tid >> 7;
    float s = 0.f;
    for (int e = half * 256; e < half * 256 + 256; ++e)
      s += bv[e] * Wo[(size_t)e * DD + j];
    red[half][tid & 127] = s;
    __syncthreads();
    if (half == 0) d0[j] = red[0][tid] + red[1][tid] + bo[j];
  }
}

// Fused megakernel: 32 rows per block, 8 waves (wave w owns cols w*64..+63 in GEMM
// phases, rows w*4..+3 in row phases). Grid = B/32 = 1024, 2 blocks/CU.
// R1 (32KB): As(head,phase0) -> t -> mbar(swizzled) -> memO.  RS (32KB): Bs/Cs staging.
__global__ __launch_bounds__(512, 4)
void mk(const float* __restrict__ q, const short* __restrict__ Atw,
        const float* __restrict__ w0, const float* __restrict__ mem,
        const int* __restrict__ mask, const short* __restrict__ Ctw,
        const float* __restrict__ d0, const float* __restrict__ sims,
        const float* __restrict__ Wg, const float* __restrict__ bgp,
        const float* __restrict__ lng, const float* __restrict__ lnb,
        float* __restrict__ outp) {
  __shared__ short R1[32 * DD];      // 32 KB
  __shared__ short RS[DD * 32];      // 32 KB
  const int tid = threadIdx.x;
  const int lane = tid & 63;
  const int w = tid >> 6;
  const int kg = lane >> 4, lr = lane & 15;
  const int bm = blockIdx.x;

  // ---------- phase 0: GEMM1  t = q @ A  (fp32 acc) ----------
  f32x4 acc[2][4] = {};
  {
    const int arow = tid >> 3, acol = (tid & 7) * 4;   // only tid<256 stage A
    const float* qbase = q + (size_t)(bm * 32 + (arow & 31)) * DD + acol;
    f32x4 qv = {};
    if (tid < 256) qv = *(const f32x4*)qbase;
    for (int kt = 0; kt < DD; kt += 32) {
#pragma unroll
      for (int c = 0; c < 4; ++c) {
        const short* src = Atw + (size_t)(c * 128 + (tid >> 2)) * DD + kt + (tid & 3) * 8;
        __builtin_amdgcn_global_load_lds((const __attribute__((address_space(1))) void*)src,
                                         (__attribute__((address_space(3))) void*)(RS + c * 4096 + w * 512),
                                         16, 0, 0);
      }
      if (tid < 256) {
        s16x4 sv;
        sv[0] = f2bf(qv[0]); sv[1] = f2bf(qv[1]); sv[2] = f2bf(qv[2]); sv[3] = f2bf(qv[3]);
        *(s16x4*)&R1[arow * 32 + acol] = sv;
      }
      __syncthreads();
      f32x4 qn = {};
      if (tid < 256 && kt + 32 < DD) qn = *(const f32x4*)(qbase + kt + 32);
      short8 av[2], bv[4];
#pragma unroll
      for (int mi = 0; mi < 2; ++mi)
        av[mi] = *(const short8*)&R1[(mi * 16 + lr) * 32 + kg * 8];
#pragma unroll
      for (int ni = 0; ni < 4; ++ni)
        bv[ni] = *(const short8*)&RS[(w * 64 + ni * 16 + lr) * 32 + kg * 8];
#pragma unroll
      for (int mi = 0; mi < 2; ++mi)
#pragma unroll
        for (int ni = 0; ni < 4; ++ni)
          acc[mi][ni] = __builtin_amdgcn_mfma_f32_16x16x32_bf16(av[mi], bv[ni], acc[mi][ni], 0, 0, 0);
      __syncthreads();
      qv = qn;
    }
  }
  // ---------- phase 1: t (+w0) -> R1[32][512] (unswizzled) ----------
#pragma unroll
  for (int ni = 0; ni < 4; ++ni) {
    const int col = w * 64 + ni * 16 + lr;
    const float b0 = w0[col];
#pragma unroll
    for (int mi = 0; mi < 2; ++mi)
#pragma unroll
      for (int r = 0; r < 4; ++r)
        R1[(mi * 16 + kg * 4 + r) * DD + col] = f2bf(acc[mi][ni][r] + b0);
  }
  __syncthreads();
  // ---------- phase 2: attention; in-place t -> mbar (swizzled write) ----------
  const float scale = 0.044194173824159216f;  // 512^-0.5
  for (int rr = 0; rr < 4; ++rr) {
    const int row = w * 4 + rr;
    const size_t b = (size_t)bm * 32 + row;
    const short8 tv = *(const short8*)&R1[row * DD + lane * 8];
    float tf[8];
#pragma unroll
    for (int i = 0; i < 8; ++i) tf[i] = bf2f(tv[i]);
    int vm = 0;
#pragma unroll
    for (int k = 0; k < KM; ++k)
      vm |= (__builtin_amdgcn_readfirstlane(mask[b * KM + k]) ? 1 : 0) << k;
    f32x4 ma[KM], mc[KM];
#pragma unroll
    for (int k = 0; k < KM; ++k)
      if (vm & (1 << k)) {
        const f32x4* mp = (const f32x4*)(mem + (b * KM + k) * DD + lane * 8);
        ma[k] = __builtin_nontemporal_load(mp);
        mc[k] = __builtin_nontemporal_load(mp + 1);
      }
    float s[KM];
#pragma unroll
    for (int k = 0; k < KM; ++k)
      if (vm & (1 << k)) {
        float p = 0.f;
#pragma unroll
        for (int i = 0; i < 4; ++i) { p += tf[i] * ma[k][i]; p += tf[4 + i] * mc[k][i]; }
#pragma unroll
        for (int off = 32; off > 0; off >>= 1) p += __shfl_xor(p, off);
        s[k] = p * scale;
      }
    float mx = -1e30f;
#pragma unroll
    for (int k = 0; k < KM; ++k)
      if (vm & (1 << k)) mx = fmaxf(mx, s[k]);
    float wk[KM], sum = 0.f;
#pragma unroll
    for (int k = 0; k < KM; ++k) {
      wk[k] = (vm & (1 << k)) ? __expf(s[k] - mx) : 0.f;
      sum += wk[k];
    }
    const float inv = 1.f / sum;
    float o[8] = {0.f,0.f,0.f,0.f,0.f,0.f,0.f,0.f};
#pragma unroll
    for (int k = 0; k < KM; ++k)
      if (vm & (1 << k)) {
        const float g = wk[k] * inv;
#pragma unroll
        for (int i = 0; i < 4; ++i) { o[i] += g * ma[k][i]; o[4 + i] += g * mc[k][i]; }
      }
    short8 ov;
#pragma unroll
    for (int i = 0; i < 8; ++i) ov[i] = f2bf(o[i]);
    *(short8*)&R1[(row * DD + lane * 8) ^ ((row & 7) << 3)] = ov;   // T2 swizzle
  }
  __syncthreads();
  // ---------- phase 3: GEMM2  memO = mbar @ C  (A from swizzled LDS) ----------
  f32x4 acc2[2][4] = {};
  for (int kt = 0; kt < DD; kt += 32) {
#pragma unroll
    for (int c = 0; c < 4; ++c) {
      const short* src = Ctw + (size_t)(c * 128 + (tid >> 2)) * DD + kt + (tid & 3) * 8;
      __builtin_amdgcn_global_load_lds((const __attribute__((address_space(1))) void*)src,
                                       (__attribute__((address_space(3))) void*)(RS + c * 4096 + w * 512),
                                       16, 0, 0);
    }
    __syncthreads();
    short8 av[2], bv[4];
#pragma unroll
    for (int mi = 0; mi < 2; ++mi) {
      const int ar = mi * 16 + lr;
      av[mi] = *(const short8*)&R1[(ar * DD + kt + kg * 8) ^ ((ar & 7) << 3)];
    }
#pragma unroll
    for (int ni = 0; ni < 4; ++ni)
      bv[ni] = *(const short8*)&RS[(w * 64 + ni * 16 + lr) * 32 + kg * 8];
#pragma unroll
    for (int mi = 0; mi < 2; ++mi)
#pragma unroll
      for (int ni = 0; ni < 4; ++ni)
        acc2[mi][ni] = __builtin_amdgcn_mfma_f32_16x16x32_bf16(av[mi], bv[ni], acc2[mi][ni], 0, 0, 0);
    __syncthreads();
  }
  // ---------- phase 4: memO (+d0) -> R1 (unswizzled) ----------
#pragma unroll
  for (int ni = 0; ni < 4; ++ni) {
    const int col = w * 64 + ni * 16 + lr;
    const float b0 = d0[col];
#pragma unroll
    for (int mi = 0; mi < 2; ++mi)
#pragma unroll
      for (int r = 0; r < 4; ++r)
        R1[(mi * 16 + kg * 4 + r) * DD + col] = f2bf(acc2[mi][ni][r] + b0);
  }
  __syncthreads();
  // ---------- phase 5: gate/conf/residual/LayerNorm -> out ----------
  {
    const float* wg1 = Wg + lane * 8;
    const float* wg2 = Wg + DD + lane * 8;
    f32x4 g1a = *(const f32x4*)wg1, g1b = *(const f32x4*)(wg1 + 4);
    f32x4 g2a = *(const f32x4*)wg2, g2b = *(const f32x4*)(wg2 + 4);
    f32x4 la = *(const f32x4*)(lng + lane * 8), lb4 = *(const f32x4*)(lng + lane * 8 + 4);
    f32x4 ba = *(const f32x4*)(lnb + lane * 8), bb4 = *(const f32x4*)(lnb + lane * 8 + 4);
    const float bgs = bgp[0];
    for (int rr = 0; rr < 4; ++rr) {
      const int row = w * 4 + rr;
      const size_t b = (size_t)bm * 32 + row;
      const float* qp = q + b * DD + lane * 8;
      f32x4 q0 = *(const f32x4*)qp;
      f32x4 q1 = *(const f32x4*)(qp + 4);
      float qf[8] = {q0[0],q0[1],q0[2],q0[3],q1[0],q1[1],q1[2],q1[3]};
      const short8 mv = *(const short8*)&R1[row * DD + lane * 8];
      float mf[8];
#pragma unroll
      for (int i = 0; i < 8; ++i) mf[i] = bf2f(mv[i]);
      float gp = qf[0]*g1a[0]+qf[1]*g1a[1]+qf[2]*g1a[2]+qf[3]*g1a[3]
               + qf[4]*g1b[0]+qf[5]*g1b[1]+qf[6]*g1b[2]+qf[7]*g1b[3]
               + mf[0]*g2a[0]+mf[1]*g2a[1]+mf[2]*g2a[2]+mf[3]*g2a[3]
               + mf[4]*g2b[0]+mf[5]*g2b[1]+mf[6]*g2b[2]+mf[7]*g2b[3];
#pragma unroll
      for (int off = 32; off > 0; off >>= 1) gp += __shfl_xor(gp, off);
      const float gate = 1.f / (1.f + __expf(-(gp + bgs)));
      float ms = sims[b * KM];
#pragma unroll
      for (int k = 1; k < KM; ++k) ms = fmaxf(ms, sims[b * KM + k]);
      const float conf = 1.f / (1.f + __expf(-(ms - 0.7f)));
      const float gc = gate * conf;
      float o[8];
      float s1 = 0.f, s2 = 0.f;
#pragma unroll
      for (int i = 0; i < 8; ++i) {
        o[i] = qf[i] + gc * mf[i];
        s1 += o[i];
        s2 += o[i] * o[i];
      }
#pragma unroll
      for (int off = 32; off > 0; off >>= 1) { s1 += __shfl_xor(s1, off); s2 += __shfl_xor(s2, off); }
      const float mu = s1 * (1.f / 512.f);
      const float var = s2 * (1.f / 512.f) - mu * mu;
      const float rs = rsqrtf(var + 1e-5f);
      f32x4 r0, r1;
#pragma unroll
      for (int i = 0; i < 4; ++i) r0[i] = (o[i] - mu) * rs * la[i] + ba[i];
#pragma unroll
      for (int i = 0; i < 4; ++i) r1[i] = (o[4 + i] - mu) * rs * lb4[i] + bb4[i];
      float* op = outp + b * DD + lane * 8;
      __builtin_nontemporal_store(r0, (f32x4*)op);
      __builtin_nontemporal_store(r1, (f32x4*)(op + 4));
    }
  }
}

extern "C" void kernel_launch(void* const* d_in, const int* in_sizes, int n_in,
                              void* d_out, int out_size, void* d_ws, size_t ws_size,
                              hipStream_t stream) {
  const float* query = (const float*)d_in[0];
  const float* mem   = (const float*)d_in[1];
  const float* sims  = (const float*)d_in[2];
  const int*   mask  = (const int*)d_in[3];
  const float* Wq = (const float*)d_in[4];
  const float* bq = (const float*)d_in[5];
  const float* Wk = (const float*)d_in[6];
  // d_in[7] = bk: irrelevant (per-row constant on scores; softmax shift-invariant)
  const float* Wv = (const float*)d_in[8];
  const float* bv = (const float*)d_in[9];
  const float* Wo = (const float*)d_in[10];
  const float* bo = (const float*)d_in[11];
  const float* Wg = (const float*)d_in[12];
  const float* bg = (const float*)d_in[13];
  const float* ln_g = (const float*)d_in[14];
  const float* ln_b = (const float*)d_in[15];
  float* out = (float*)d_out;

  char* ws = (char*)d_ws;
  short* At = (short*)ws;                               // 512 KB  At[j][i] = (WqWk^T)[i][j] (n-major)
  short* Ct = At + (size_t)DD * DD;                     // 512 KB  Ct[j][d] = (WvWo)[d][j]
  float* w0 = (float*)(Ct + (size_t)DD * DD);           // 2 KB
  float* d0 = w0 + DD;                                  // 2 KB

  dim3 wblk(16, 16), wgrd(32, 32);
  wprep<false><<<wgrd, wblk, 0, stream>>>(Wk, Wq, At);
  wprep<true ><<<wgrd, wblk, 0, stream>>>(Wo, Wv, Ct);
  biasprep2<<<dim3(132), dim3(256), 0, stream>>>(bq, Wk, bv, Wo, bo, w0, d0);

  mk<<<dim3(B_ROWS / 32), dim3(512), 0, stream>>>(query, At, w0, mem, mask,
                                                  Ct, d0, sims, Wg, bg, ln_g, ln_b, out);
}

// Round 6
// 177.967 us; speedup vs baseline: 1.4994x; 1.0268x over previous
//
#include <hip/hip_runtime.h>

#define DD 512
#define KM 5
#define B_ROWS 32768

typedef __attribute__((ext_vector_type(8))) short short8;
typedef __attribute__((ext_vector_type(4))) short s16x4;
typedef __attribute__((ext_vector_type(4))) float f32x4;

static __device__ __forceinline__ short f2bf(float x) {
  unsigned u = __builtin_bit_cast(unsigned, x);
  u = (u + 0x7fffu + ((u >> 16) & 1u)) >> 16;
  return (short)u;
}
static __device__ __forceinline__ float bf2f(short s) {
  unsigned u = ((unsigned)(unsigned short)s) << 16;
  return __builtin_bit_cast(float, u);
}

// raw barrier + counted vmcnt (T3-minimum); "memory" clobber orders LDS/global ops
#define SYNC0() do { asm volatile("s_waitcnt vmcnt(0) lgkmcnt(0)" ::: "memory"); __builtin_amdgcn_s_barrier(); } while (0)
#define SYNC1() do { asm volatile("s_waitcnt vmcnt(1) lgkmcnt(0)" ::: "memory"); __builtin_amdgcn_s_barrier(); } while (0)

// P[j][i] = sum_l X(j,l) * Y(i,l);  X(j,l) = XT ? X[l*DD+j] : X[j*DD+l]
template<bool XT>
__global__ __launch_bounds__(256)
void wprep(const float* __restrict__ X, const float* __restrict__ Y, short* __restrict__ P) {
  __shared__ float Xs[16][17];
  __shared__ float Ys[16][17];
  const int tx = threadIdx.x, ty = threadIdx.y;
  const int i0 = blockIdx.x * 16, j0 = blockIdx.y * 16;
  float acc = 0.f;
  for (int l0 = 0; l0 < DD; l0 += 16) {
    if (XT) {
      Xs[tx][ty] = X[(size_t)(l0 + ty) * DD + (j0 + tx)];
    } else {
      Xs[ty][tx] = X[(size_t)(j0 + ty) * DD + (l0 + tx)];
    }
    Ys[ty][tx] = Y[(size_t)(i0 + ty) * DD + (l0 + tx)];
    __syncthreads();
#pragma unroll
    for (int l = 0; l < 16; ++l) acc += Xs[ty][l] * Ys[tx][l];
    __syncthreads();
  }
  P[(size_t)(j0 + ty) * DD + (i0 + tx)] = f2bf(acc);
}

// blocks 0..127: w0[j];  blocks 128..131: d0[j]
__global__ __launch_bounds__(256)
void biasprep2(const float* __restrict__ bq, const float* __restrict__ Wk,
               const float* __restrict__ bv, const float* __restrict__ Wo,
               const float* __restrict__ bo, float* __restrict__ w0,
               float* __restrict__ d0) {
  __shared__ float red[2][128];
  const int tid = threadIdx.x;
  if (blockIdx.x < 128) {
    const int j = blockIdx.x * 4 + (tid >> 6);
    const int lane = tid & 63;
    const float* r = Wk + (size_t)j * DD + lane * 8;
    f32x4 a = *(const f32x4*)r;
    f32x4 c = *(const f32x4*)(r + 4);
    const float* bp = bq + lane * 8;
    f32x4 ba = *(const f32x4*)bp;
    f32x4 bc = *(const f32x4*)(bp + 4);
    float s = a[0]*ba[0] + a[1]*ba[1] + a[2]*ba[2] + a[3]*ba[3]
            + c[0]*bc[0] + c[1]*bc[1] + c[2]*bc[2] + c[3]*bc[3];
#pragma unroll
    for (int off = 32; off > 0; off >>= 1) s += __shfl_xor(s, off);
    if (lane == 0) w0[j] = s;
  } else {
    const int j = (blockIdx.x - 128) * 128 + (tid & 127);
    const int half = tid >> 7;
    float s = 0.f;
    for (int e = half * 256; e < half * 256 + 256; ++e)
      s += bv[e] * Wo[(size_t)e * DD + j];
    red[half][tid & 127] = s;
    __syncthreads();
    if (half == 0) d0[j] = red[0][tid] + red[1][tid] + bo[j];
  }
}

// stage one [512 x 32] bf16 weight k-slice into RS[BUF], source-preswizzled so the
// swizzled ds_read below sees original content (both-sides rule)
#define STAGE_W(MAT, TI, BUF) do {                                                 \
  _Pragma("unroll") for (int c = 0; c < 4; ++c) {                                  \
    const short* _src = (MAT) + (size_t)(c * 128 + (tid >> 2)) * DD + (TI) * 32    \
                        + (((tid & 3) * 8) ^ (((tid >> 2) & 3) << 3));             \
    __builtin_amdgcn_global_load_lds(                                              \
        (const __attribute__((address_space(1))) void*)_src,                       \
        (__attribute__((address_space(3))) void*)(&RS[BUF][c * 4096 + w * 512]),   \
        16, 0, 0);                                                                 \
  } } while (0)

#define WRITE_A(DST, QV) do {                                                      \
  s16x4 _sv;                                                                       \
  _sv[0] = f2bf((QV)[0]); _sv[1] = f2bf((QV)[1]);                                  \
  _sv[2] = f2bf((QV)[2]); _sv[3] = f2bf((QV)[3]);                                  \
  *(s16x4*)&(DST)[arow * 32 + (acol ^ ((arow & 3) << 3))] = _sv; } while (0)

// softmax+weighted-sum finisher; writes mbar row into R1 with (row&7)<<3 swizzle
#define ROW_FINISH(SV, MA, MC, VM, ROW)                                     \
    {                                                                       \
      float mx = -1e30f;                                                    \
      _Pragma("unroll") for (int k = 0; k < KM; ++k)                        \
        if ((VM) & (1 << k)) mx = fmaxf(mx, SV[k]);                         \
      float wk[KM]; float sum = 0.f;                                        \
      _Pragma("unroll") for (int k = 0; k < KM; ++k) {                      \
        wk[k] = ((VM) & (1 << k)) ? __expf(SV[k] - mx) : 0.f;               \
        sum += wk[k];                                                       \
      }                                                                     \
      const float inv = 1.f / sum;                                          \
      float o[8] = {0.f,0.f,0.f,0.f,0.f,0.f,0.f,0.f};                       \
      _Pragma("unroll") for (int k = 0; k < KM; ++k)                        \
        if ((VM) & (1 << k)) {                                              \
          const float g = wk[k] * inv;                                      \
          _Pragma("unroll") for (int i = 0; i < 4; ++i) {                   \
            o[i] += g * MA[k][i]; o[4 + i] += g * MC[k][i];                 \
          }                                                                 \
        }                                                                   \
      short8 ov;                                                            \
      _Pragma("unroll") for (int i = 0; i < 8; ++i) ov[i] = f2bf(o[i]);     \
      *(short8*)&R1[((ROW) * DD + lane * 8) ^ (((ROW) & 7) << 3)] = ov;     \
    }

// Fused megakernel, 64 rows/block, 8 waves, pipelined staging.
// R1 64KB: A-dbuf -> t -> mbar(swz) -> memO.  RS 2x32KB: weight k-slice dbuf.
__global__ __launch_bounds__(512, 2)
void mk(const float* __restrict__ q, const short* __restrict__ Atw,
        const float* __restrict__ w0, const float* __restrict__ mem,
        const int* __restrict__ mask, const short* __restrict__ Ctw,
        const float* __restrict__ d0, const float* __restrict__ sims,
        const float* __restrict__ Wg, const float* __restrict__ bgp,
        const float* __restrict__ lng, const float* __restrict__ lnb,
        float* __restrict__ outp) {
  __shared__ short R1[64 * DD];      // 64 KB
  __shared__ short RS[2][DD * 32];   // 2 x 32 KB
  const int tid = threadIdx.x;
  const int lane = tid & 63;
  const int w = tid >> 6;
  const int kg = lane >> 4, lr = lane & 15;
  const int bm = blockIdx.x;

  // ---------- phase 0: GEMM1  t = q @ A  (pipelined) ----------
  f32x4 acc[4][4] = {};
  const int arow = tid >> 3, acol = (tid & 7) * 4;
  const float* qbase = q + (size_t)(bm * 64 + arow) * DD + acol;
  {
    STAGE_W(Atw, 0, 0);
    __builtin_amdgcn_sched_barrier(0);
    f32x4 qv0 = *(const f32x4*)qbase;
    f32x4 qv_a = *(const f32x4*)(qbase + 32);
    WRITE_A(R1, qv0);
    SYNC1();                                  // qv_a stays in flight
    for (int ki = 0; ki < 16; ++ki) {
      const int cur = ki & 1;
      const short* Asc = R1 + cur * 2048;
      if (ki < 15) {
        STAGE_W(Atw, ki + 1, cur ^ 1);
        __builtin_amdgcn_sched_barrier(0);    // keep stage loads oldest
        WRITE_A(R1 + (cur ^ 1) * 2048, qv_a);
        if (ki < 14) qv_a = *(const f32x4*)(qbase + (ki + 2) * 32);
      }
      short8 av[4], bvv[4];
#pragma unroll
      for (int mi = 0; mi < 4; ++mi) {
        const int ar = mi * 16 + lr;
        av[mi] = *(const short8*)&Asc[ar * 32 + ((kg * 8) ^ ((lr & 3) << 3))];
      }
#pragma unroll
      for (int ni = 0; ni < 4; ++ni) {
        const int row = w * 64 + ni * 16 + lr;
        bvv[ni] = *(const short8*)&RS[cur][row * 32 + ((kg * 8) ^ ((lr & 3) << 3))];
      }
#pragma unroll
      for (int mi = 0; mi < 4; ++mi)
#pragma unroll
        for (int ni = 0; ni < 4; ++ni)
          acc[mi][ni] = __builtin_amdgcn_mfma_f32_16x16x32_bf16(av[mi], bvv[ni], acc[mi][ni], 0, 0, 0);
      if (ki < 14) { SYNC1(); } else { SYNC0(); }
    }
  }
  // ---------- phase 1: t (+w0) -> R1[64][512] unswizzled ----------
#pragma unroll
  for (int ni = 0; ni < 4; ++ni) {
    const int col = w * 64 + ni * 16 + lr;
    const float b0 = w0[col];
#pragma unroll
    for (int mi = 0; mi < 4; ++mi)
#pragma unroll
      for (int r = 0; r < 4; ++r)
        R1[(mi * 16 + kg * 4 + r) * DD + col] = f2bf(acc[mi][ni][r] + b0);
  }
  SYNC0();
  // ---------- phase 2: attention (2-row pipelined); GEMM2 tile-0 stage overlaps ----------
  STAGE_W(Ctw, 0, 0);
  const float scale = 0.044194173824159216f;  // 512^-0.5
  for (int rr = 0; rr < 8; rr += 2) {
    const int row0 = w * 8 + rr;
    const size_t b0 = (size_t)bm * 64 + row0;
    const short8 tv0 = *(const short8*)&R1[row0 * DD + lane * 8];
    const short8 tv1 = *(const short8*)&R1[(row0 + 1) * DD + lane * 8];
    float tf0[8], tf1[8];
#pragma unroll
    for (int i = 0; i < 8; ++i) { tf0[i] = bf2f(tv0[i]); tf1[i] = bf2f(tv1[i]); }
    int vm0 = 0, vm1 = 0;
#pragma unroll
    for (int k = 0; k < KM; ++k) {
      vm0 |= (__builtin_amdgcn_readfirstlane(mask[b0 * KM + k]) ? 1 : 0) << k;
      vm1 |= (__builtin_amdgcn_readfirstlane(mask[(b0 + 1) * KM + k]) ? 1 : 0) << k;
    }
    f32x4 ma0[KM], mc0[KM], ma1[KM], mc1[KM];
#pragma unroll
    for (int k = 0; k < KM; ++k) {
      if (vm0 & (1 << k)) {
        const f32x4* mp = (const f32x4*)(mem + (b0 * KM + k) * DD + lane * 8);
        ma0[k] = __builtin_nontemporal_load(mp);
        mc0[k] = __builtin_nontemporal_load(mp + 1);
      }
      if (vm1 & (1 << k)) {
        const f32x4* mp = (const f32x4*)(mem + ((b0 + 1) * KM + k) * DD + lane * 8);
        ma1[k] = __builtin_nontemporal_load(mp);
        mc1[k] = __builtin_nontemporal_load(mp + 1);
      }
    }
    float s0[KM], s1[KM];
#pragma unroll
    for (int k = 0; k < KM; ++k) {
      if (vm0 & (1 << k)) {
        float p = 0.f;
#pragma unroll
        for (int i = 0; i < 4; ++i) { p += tf0[i] * ma0[k][i]; p += tf0[4 + i] * mc0[k][i]; }
#pragma unroll
        for (int off = 32; off > 0; off >>= 1) p += __shfl_xor(p, off);
        s0[k] = p * scale;
      }
      if (vm1 & (1 << k)) {
        float p = 0.f;
#pragma unroll
        for (int i = 0; i < 4; ++i) { p += tf1[i] * ma1[k][i]; p += tf1[4 + i] * mc1[k][i]; }
#pragma unroll
        for (int off = 32; off > 0; off >>= 1) p += __shfl_xor(p, off);
        s1[k] = p * scale;
      }
    }
    ROW_FINISH(s0, ma0, mc0, vm0, row0)
    ROW_FINISH(s1, ma1, mc1, vm1, (row0 + 1))
  }
  SYNC0();
  // ---------- phase 3: GEMM2  memO = mbar @ C  (A from swizzled R1, pipelined) ----------
  f32x4 acc2[4][4] = {};
  for (int ki = 0; ki < 16; ++ki) {
    const int cur = ki & 1;
    if (ki < 15) STAGE_W(Ctw, ki + 1, cur ^ 1);
    short8 av[4], bvv[4];
#pragma unroll
    for (int mi = 0; mi < 4; ++mi) {
      const int ar = mi * 16 + lr;
      av[mi] = *(const short8*)&R1[(ar * DD + ki * 32 + kg * 8) ^ ((ar & 7) << 3)];
    }
#pragma unroll
    for (int ni = 0; ni < 4; ++ni) {
      const int row = w * 64 + ni * 16 + lr;
      bvv[ni] = *(const short8*)&RS[cur][row * 32 + ((kg * 8) ^ ((lr & 3) << 3))];
    }
#pragma unroll
    for (int mi = 0; mi < 4; ++mi)
#pragma unroll
      for (int ni = 0; ni < 4; ++ni)
        acc2[mi][ni] = __builtin_amdgcn_mfma_f32_16x16x32_bf16(av[mi], bvv[ni], acc2[mi][ni], 0, 0, 0);
    SYNC0();
  }
  // ---------- phase 4: memO (+d0) -> R1 unswizzled ----------
#pragma unroll
  for (int ni = 0; ni < 4; ++ni) {
    const int col = w * 64 + ni * 16 + lr;
    const float b0 = d0[col];
#pragma unroll
    for (int mi = 0; mi < 4; ++mi)
#pragma unroll
      for (int r = 0; r < 4; ++r)
        R1[(mi * 16 + kg * 4 + r) * DD + col] = f2bf(acc2[mi][ni][r] + b0);
  }
  SYNC0();
  // ---------- phase 5: gate/conf/residual/LayerNorm -> out ----------
  {
    const float* wg1 = Wg + lane * 8;
    const float* wg2 = Wg + DD + lane * 8;
    f32x4 g1a = *(const f32x4*)wg1, g1b = *(const f32x4*)(wg1 + 4);
    f32x4 g2a = *(const f32x4*)wg2, g2b = *(const f32x4*)(wg2 + 4);
    f32x4 la = *(const f32x4*)(lng + lane * 8), lb4 = *(const f32x4*)(lng + lane * 8 + 4);
    f32x4 ba = *(const f32x4*)(lnb + lane * 8), bb4 = *(const f32x4*)(lnb + lane * 8 + 4);
    const float bgs = bgp[0];
    for (int rr = 0; rr < 8; ++rr) {
      const int row = w * 8 + rr;
      const size_t b = (size_t)bm * 64 + row;
      const float* qp = q + b * DD + lane * 8;
      f32x4 q0 = *(const f32x4*)qp;
      f32x4 q1 = *(const f32x4*)(qp + 4);
      float qf[8] = {q0[0],q0[1],q0[2],q0[3],q1[0],q1[1],q1[2],q1[3]};
      const short8 mv = *(const short8*)&R1[row * DD + lane * 8];
      float mf[8];
#pragma unroll
      for (int i = 0; i < 8; ++i) mf[i] = bf2f(mv[i]);
      float gp = qf[0]*g1a[0]+qf[1]*g1a[1]+qf[2]*g1a[2]+qf[3]*g1a[3]
               + qf[4]*g1b[0]+qf[5]*g1b[1]+qf[6]*g1b[2]+qf[7]*g1b[3]
               + mf[0]*g2a[0]+mf[1]*g2a[1]+mf[2]*g2a[2]+mf[3]*g2a[3]
               + mf[4]*g2b[0]+mf[5]*g2b[1]+mf[6]*g2b[2]+mf[7]*g2b[3];
#pragma unroll
      for (int off = 32; off > 0; off >>= 1) gp += __shfl_xor(gp, off);
      const float gate = 1.f / (1.f + __expf(-(gp + bgs)));
      float ms = sims[b * KM];
#pragma unroll
      for (int k = 1; k < KM; ++k) ms = fmaxf(ms, sims[b * KM + k]);
      const float conf = 1.f / (1.f + __expf(-(ms - 0.7f)));
      const float gc = gate * conf;
      float o[8];
      float s1 = 0.f, s2 = 0.f;
#pragma unroll
      for (int i = 0; i < 8; ++i) {
        o[i] = qf[i] + gc * mf[i];
        s1 += o[i];
        s2 += o[i] * o[i];
      }
#pragma unroll
      for (int off = 32; off > 0; off >>= 1) { s1 += __shfl_xor(s1, off); s2 += __shfl_xor(s2, off); }
      const float mu = s1 * (1.f / 512.f);
      const float var = s2 * (1.f / 512.f) - mu * mu;
      const float rs = rsqrtf(var + 1e-5f);
      f32x4 r0, r1;
#pragma unroll
      for (int i = 0; i < 4; ++i) r0[i] = (o[i] - mu) * rs * la[i] + ba[i];
#pragma unroll
      for (int i = 0; i < 4; ++i) r1[i] = (o[4 + i] - mu) * rs * lb4[i] + bb4[i];
      float* op = outp + b * DD + lane * 8;
      __builtin_nontemporal_store(r0, (f32x4*)op);
      __builtin_nontemporal_store(r1, (f32x4*)(op + 4));
    }
  }
}

extern "C" void kernel_launch(void* const* d_in, const int* in_sizes, int n_in,
                              void* d_out, int out_size, void* d_ws, size_t ws_size,
                              hipStream_t stream) {
  const float* query = (const float*)d_in[0];
  const float* mem   = (const float*)d_in[1];
  const float* sims  = (const float*)d_in[2];
  const int*   mask  = (const int*)d_in[3];
  const float* Wq = (const float*)d_in[4];
  const float* bq = (const float*)d_in[5];
  const float* Wk = (const float*)d_in[6];
  // d_in[7] = bk: irrelevant (per-row constant on scores; softmax shift-invariant)
  const float* Wv = (const float*)d_in[8];
  const float* bv = (const float*)d_in[9];
  const float* Wo = (const float*)d_in[10];
  const float* bo = (const float*)d_in[11];
  const float* Wg = (const float*)d_in[12];
  const float* bg = (const float*)d_in[13];
  const float* ln_g = (const float*)d_in[14];
  const float* ln_b = (const float*)d_in[15];
  float* out = (float*)d_out;

  char* ws = (char*)d_ws;
  short* At = (short*)ws;                               // 512 KB  At[j][i] = (WqWk^T)[i][j] (n-major)
  short* Ct = At + (size_t)DD * DD;                     // 512 KB  Ct[j][d] = (WvWo)[d][j]
  float* w0 = (float*)(Ct + (size_t)DD * DD);           // 2 KB
  float* d0 = w0 + DD;                                  // 2 KB

  dim3 wblk(16, 16), wgrd(32, 32);
  wprep<false><<<wgrd, wblk, 0, stream>>>(Wk, Wq, At);
  wprep<true ><<<wgrd, wblk, 0, stream>>>(Wo, Wv, Ct);
  biasprep2<<<dim3(132), dim3(256), 0, stream>>>(bq, Wk, bv, Wo, bo, w0, d0);

  mk<<<dim3(B_ROWS / 64), dim3(512), 0, stream>>>(query, At, w0, mem, mask,
                                                  Ct, d0, sims, Wg, bg, ln_g, ln_b, out);
}

// Round 7
// 156.459 us; speedup vs baseline: 1.7055x; 1.1375x over previous
//
#include <hip/hip_runtime.h>

#define DD 512
#define KM 5
#define B_ROWS 32768

typedef __attribute__((ext_vector_type(8))) short short8;
typedef __attribute__((ext_vector_type(4))) short s16x4;
typedef __attribute__((ext_vector_type(4))) float f32x4;

static __device__ __forceinline__ short f2bf(float x) {
  unsigned u = __builtin_bit_cast(unsigned, x);
  u = (u + 0x7fffu + ((u >> 16) & 1u)) >> 16;
  return (short)u;
}
static __device__ __forceinline__ float bf2f(short s) {
  unsigned u = ((unsigned)(unsigned short)s) << 16;
  return __builtin_bit_cast(float, u);
}

// raw barrier + counted vmcnt; "memory" clobber orders LDS/global ops
#define SYNC0() do { asm volatile("s_waitcnt vmcnt(0) lgkmcnt(0)" ::: "memory"); __builtin_amdgcn_s_barrier(); } while (0)
#define SYNC2() do { asm volatile("s_waitcnt vmcnt(2) lgkmcnt(0)" ::: "memory"); __builtin_amdgcn_s_barrier(); } while (0)
#define BAR_LGKM() do { asm volatile("s_waitcnt lgkmcnt(0)" ::: "memory"); __builtin_amdgcn_s_barrier(); } while (0)

// ---------------- fused prep: At, Ct, w0, d0 in ONE launch ----------------
// blocks 0..1023: At tile; 1024..2047: Ct tile; 2048..2175: w0; 2176..2179: d0
__global__ __launch_bounds__(256)
void prep(const float* __restrict__ Wq, const float* __restrict__ bq,
          const float* __restrict__ Wk, const float* __restrict__ Wv,
          const float* __restrict__ Wo, const float* __restrict__ bo,
          const float* __restrict__ bv,
          short* __restrict__ At, short* __restrict__ Ct,
          float* __restrict__ w0, float* __restrict__ d0) {
  __shared__ float Xs[16][17];
  __shared__ float Ys[16][17];
  __shared__ float red[2][128];
  const int tid = threadIdx.x;
  const int blk = blockIdx.x;
  if (blk < 2048) {
    const bool isC = blk >= 1024;
    const int b = blk & 1023;
    const int i0 = (b & 31) * 16, j0 = (b >> 5) * 16;
    const int tx = tid & 15, ty = tid >> 4;
    const float* X = isC ? Wo : Wk;
    const float* Y = isC ? Wv : Wq;
    float acc = 0.f;
    for (int l0 = 0; l0 < DD; l0 += 16) {
      if (isC) Xs[tx][ty] = X[(size_t)(l0 + ty) * DD + (j0 + tx)];
      else     Xs[ty][tx] = X[(size_t)(j0 + ty) * DD + (l0 + tx)];
      Ys[ty][tx] = Y[(size_t)(i0 + ty) * DD + (l0 + tx)];
      __syncthreads();
#pragma unroll
      for (int l = 0; l < 16; ++l) acc += Xs[ty][l] * Ys[tx][l];
      __syncthreads();
    }
    short* P = isC ? Ct : At;
    P[(size_t)(j0 + ty) * DD + (i0 + tx)] = f2bf(acc);
  } else if (blk < 2176) {
    const int j = (blk - 2048) * 4 + (tid >> 6);
    const int lane = tid & 63;
    const float* r = Wk + (size_t)j * DD + lane * 8;
    f32x4 a = *(const f32x4*)r;
    f32x4 c = *(const f32x4*)(r + 4);
    const float* bp = bq + lane * 8;
    f32x4 ba = *(const f32x4*)bp;
    f32x4 bc = *(const f32x4*)(bp + 4);
    float s = a[0]*ba[0] + a[1]*ba[1] + a[2]*ba[2] + a[3]*ba[3]
            + c[0]*bc[0] + c[1]*bc[1] + c[2]*bc[2] + c[3]*bc[3];
#pragma unroll
    for (int off = 32; off > 0; off >>= 1) s += __shfl_xor(s, off);
    if (lane == 0) w0[j] = s;
  } else {
    const int j = (blk - 2176) * 128 + (tid & 127);
    const int half = tid >> 7;
    float s = 0.f;
    for (int e = half * 256; e < half * 256 + 256; ++e)
      s += bv[e] * Wo[(size_t)e * DD + j];
    red[half][tid & 127] = s;
    __syncthreads();
    if (half == 0) d0[j] = red[0][tid] + red[1][tid] + bo[j];
  }
}

// stage one [512 x 32] bf16 weight k-slice into DST, source-preswizzled so the
// swizzled ds_read sees original content (both-sides rule)
#define STAGE_W(MAT, TI, DST) do {                                                 \
  _Pragma("unroll") for (int c = 0; c < 4; ++c) {                                  \
    const short* _src = (MAT) + (size_t)(c * 128 + (tid >> 2)) * DD + (TI) * 32    \
                        + (((tid & 3) * 8) ^ (((tid >> 2) & 3) << 3));             \
    __builtin_amdgcn_global_load_lds(                                              \
        (const __attribute__((address_space(1))) void*)_src,                       \
        (__attribute__((address_space(3))) void*)(&(DST)[c * 4096 + w * 512]),     \
        16, 0, 0);                                                                 \
  } } while (0)

// write one 128x32 A k-slice row-chunk (8 bf16) from two f32x4
#define WRITE_A(DST, QLO, QHI) do {                                                \
  short8 _sv;                                                                      \
  _sv[0]=f2bf((QLO)[0]); _sv[1]=f2bf((QLO)[1]); _sv[2]=f2bf((QLO)[2]); _sv[3]=f2bf((QLO)[3]); \
  _sv[4]=f2bf((QHI)[0]); _sv[5]=f2bf((QHI)[1]); _sv[6]=f2bf((QHI)[2]); _sv[7]=f2bf((QHI)[3]); \
  *(short8*)&(DST)[arow * 32 + (acol ^ ((arow & 3) << 3))] = _sv; } while (0)

// softmax+weighted-sum finisher; writes mbar row into R1 with (row&7)<<3 swizzle
#define ROW_FINISH(SV, MA, MC, VM, ROW)                                     \
    {                                                                       \
      float mx = -1e30f;                                                    \
      _Pragma("unroll") for (int k = 0; k < KM; ++k)                        \
        if ((VM) & (1 << k)) mx = fmaxf(mx, SV[k]);                         \
      float wk[KM]; float sum = 0.f;                                        \
      _Pragma("unroll") for (int k = 0; k < KM; ++k) {                      \
        wk[k] = ((VM) & (1 << k)) ? __expf(SV[k] - mx) : 0.f;               \
        sum += wk[k];                                                       \
      }                                                                     \
      const float inv = 1.f / sum;                                          \
      float o[8] = {0.f,0.f,0.f,0.f,0.f,0.f,0.f,0.f};                       \
      _Pragma("unroll") for (int k = 0; k < KM; ++k)                        \
        if ((VM) & (1 << k)) {                                              \
          const float g = wk[k] * inv;                                      \
          _Pragma("unroll") for (int i = 0; i < 4; ++i) {                   \
            o[i] += g * MA[k][i]; o[4 + i] += g * MC[k][i];                 \
          }                                                                 \
        }                                                                   \
      short8 ov;                                                            \
      _Pragma("unroll") for (int i = 0; i < 8; ++i) ov[i] = f2bf(o[i]);     \
      *(short8*)&R1[((ROW) * DD + lane * 8) ^ (((ROW) & 7) << 3)] = ov;     \
    }

// Fused megakernel, 128 rows/block, 8 waves, grid 256 (1 block/CU).
// LDS 160 KB: R1 128 KB (A-dbuf+RS1 during GEMM1 -> t -> mbar(swz) -> memO), RS 32 KB.
__global__ __launch_bounds__(512, 2)
void mk(const float* __restrict__ q, const short* __restrict__ Atw,
        const float* __restrict__ w0, const float* __restrict__ mem,
        const int* __restrict__ mask, const short* __restrict__ Ctw,
        const float* __restrict__ d0, const float* __restrict__ sims,
        const float* __restrict__ Wg, const float* __restrict__ bgp,
        const float* __restrict__ lng, const float* __restrict__ lnb,
        float* __restrict__ outp) {
  __shared__ short R1[128 * DD];     // 128 KB
  __shared__ short RS[DD * 32];      // 32 KB
  const int tid = threadIdx.x;
  const int lane = tid & 63;
  const int w = tid >> 6;
  const int kg = lane >> 4, lr = lane & 15;
  const int bm = blockIdx.x;

  short* As0 = R1;                   // [128][32] 8 KB
  short* As1 = R1 + 4096;            // 8 KB
  short* RS1 = R1 + 8192;            // 32 KB (GEMM1 second B buffer)

  // ---------- phase 0: GEMM1  t = q @ A  (pipelined, dbuf) ----------
  f32x4 acc[8][4] = {};
  const int arow = tid >> 2, acol = (tid & 3) * 8;
  const float* qbase = q + (size_t)(bm * 128 + arow) * DD + acol;
  {
    STAGE_W(Atw, 0, RS);
    __builtin_amdgcn_sched_barrier(0);
    f32x4 q0a = *(const f32x4*)qbase;
    f32x4 q0b = *(const f32x4*)(qbase + 4);
    WRITE_A(As0, q0a, q0b);
    f32x4 qA = *(const f32x4*)(qbase + 32);
    f32x4 qB = *(const f32x4*)(qbase + 36);
    SYNC2();                                  // stage0 done; qA/qB in flight
    for (int ki = 0; ki < 16; ++ki) {
      const short* Asc = (ki & 1) ? As1 : As0;
      short* Asn = (ki & 1) ? As0 : As1;
      const short* RSc = (ki & 1) ? RS1 : RS;
      short* RSn = (ki & 1) ? RS : RS1;
      short8 av[8], bvv[4];
#pragma unroll
      for (int mi = 0; mi < 8; ++mi) {
        const int ar = mi * 16 + lr;
        av[mi] = *(const short8*)&Asc[ar * 32 + ((kg * 8) ^ ((lr & 3) << 3))];
      }
#pragma unroll
      for (int ni = 0; ni < 4; ++ni) {
        const int row = w * 64 + ni * 16 + lr;
        bvv[ni] = *(const short8*)&RSc[row * 32 + ((kg * 8) ^ ((lr & 3) << 3))];
      }
      if (ki < 15) {
        WRITE_A(Asn, qA, qB);
        STAGE_W(Atw, ki + 1, RSn);
        __builtin_amdgcn_sched_barrier(0);    // keep stage loads oldest
        if (ki < 14) {
          qA = *(const f32x4*)(qbase + (ki + 2) * 32);
          qB = *(const f32x4*)(qbase + (ki + 2) * 32 + 4);
        }
      }
#pragma unroll
      for (int mi = 0; mi < 8; ++mi)
#pragma unroll
        for (int ni = 0; ni < 4; ++ni)
          acc[mi][ni] = __builtin_amdgcn_mfma_f32_16x16x32_bf16(av[mi], bvv[ni], acc[mi][ni], 0, 0, 0);
      if (ki < 14) { SYNC2(); } else { SYNC0(); }
    }
  }
  // ---------- phase 1: t (+w0) -> R1[128][512] unswizzled ----------
#pragma unroll
  for (int ni = 0; ni < 4; ++ni) {
    const int col = w * 64 + ni * 16 + lr;
    const float b0 = w0[col];
#pragma unroll
    for (int mi = 0; mi < 8; ++mi)
#pragma unroll
      for (int r = 0; r < 4; ++r)
        R1[(mi * 16 + kg * 4 + r) * DD + col] = f2bf(acc[mi][ni][r] + b0);
  }
  BAR_LGKM();
  // ---------- phase 2: attention; t -> mbar in place; Ct tile0 stage overlaps ----------
  STAGE_W(Ctw, 0, RS);
  const float scale = 0.044194173824159216f;  // 512^-0.5
  for (int rr = 0; rr < 16; rr += 2) {
    const int row0 = w * 16 + rr;
    const size_t b0 = (size_t)bm * 128 + row0;
    const short8 tv0 = *(const short8*)&R1[row0 * DD + lane * 8];
    const short8 tv1 = *(const short8*)&R1[(row0 + 1) * DD + lane * 8];
    float tf0[8], tf1[8];
#pragma unroll
    for (int i = 0; i < 8; ++i) { tf0[i] = bf2f(tv0[i]); tf1[i] = bf2f(tv1[i]); }
    int vm0 = 0, vm1 = 0;
#pragma unroll
    for (int k = 0; k < KM; ++k) {
      vm0 |= (__builtin_amdgcn_readfirstlane(mask[b0 * KM + k]) ? 1 : 0) << k;
      vm1 |= (__builtin_amdgcn_readfirstlane(mask[(b0 + 1) * KM + k]) ? 1 : 0) << k;
    }
    f32x4 ma0[KM], mc0[KM], ma1[KM], mc1[KM];
#pragma unroll
    for (int k = 0; k < KM; ++k) {
      if (vm0 & (1 << k)) {
        const f32x4* mp = (const f32x4*)(mem + (b0 * KM + k) * DD + lane * 8);
        ma0[k] = __builtin_nontemporal_load(mp);
        mc0[k] = __builtin_nontemporal_load(mp + 1);
      }
      if (vm1 & (1 << k)) {
        const f32x4* mp = (const f32x4*)(mem + ((b0 + 1) * KM + k) * DD + lane * 8);
        ma1[k] = __builtin_nontemporal_load(mp);
        mc1[k] = __builtin_nontemporal_load(mp + 1);
      }
    }
    float s0[KM], s1[KM];
#pragma unroll
    for (int k = 0; k < KM; ++k) {
      if (vm0 & (1 << k)) {
        float p = 0.f;
#pragma unroll
        for (int i = 0; i < 4; ++i) { p += tf0[i] * ma0[k][i]; p += tf0[4 + i] * mc0[k][i]; }
#pragma unroll
        for (int off = 32; off > 0; off >>= 1) p += __shfl_xor(p, off);
        s0[k] = p * scale;
      }
      if (vm1 & (1 << k)) {
        float p = 0.f;
#pragma unroll
        for (int i = 0; i < 4; ++i) { p += tf1[i] * ma1[k][i]; p += tf1[4 + i] * mc1[k][i]; }
#pragma unroll
        for (int off = 32; off > 0; off >>= 1) p += __shfl_xor(p, off);
        s1[k] = p * scale;
      }
    }
    ROW_FINISH(s0, ma0, mc0, vm0, row0)
    ROW_FINISH(s1, ma1, mc1, vm1, (row0 + 1))
  }
  SYNC0();
  // ---------- phase 3: GEMM2  memO = mbar @ C  (A from swizzled R1; RS single-buffered) ----------
  f32x4 acc2[8][4] = {};
  for (int ki = 0; ki < 16; ++ki) {
    short8 av[8], bvv[4];
#pragma unroll
    for (int mi = 0; mi < 8; ++mi) {
      const int ar = mi * 16 + lr;
      av[mi] = *(const short8*)&R1[(ar * DD + ki * 32 + kg * 8) ^ ((ar & 7) << 3)];
    }
#pragma unroll
    for (int ni = 0; ni < 4; ++ni) {
      const int row = w * 64 + ni * 16 + lr;
      bvv[ni] = *(const short8*)&RS[row * 32 + ((kg * 8) ^ ((lr & 3) << 3))];
    }
    BAR_LGKM();                        // all waves' RS reads complete before overwrite
    if (ki < 15) STAGE_W(Ctw, ki + 1, RS);
#pragma unroll
    for (int mi = 0; mi < 8; ++mi)
#pragma unroll
      for (int ni = 0; ni < 4; ++ni)
        acc2[mi][ni] = __builtin_amdgcn_mfma_f32_16x16x32_bf16(av[mi], bvv[ni], acc2[mi][ni], 0, 0, 0);
    SYNC0();
  }
  // ---------- phase 4: memO (+d0) -> R1 unswizzled ----------
#pragma unroll
  for (int ni = 0; ni < 4; ++ni) {
    const int col = w * 64 + ni * 16 + lr;
    const float b0 = d0[col];
#pragma unroll
    for (int mi = 0; mi < 8; ++mi)
#pragma unroll
      for (int r = 0; r < 4; ++r)
        R1[(mi * 16 + kg * 4 + r) * DD + col] = f2bf(acc2[mi][ni][r] + b0);
  }
  BAR_LGKM();
  // ---------- phase 5: gate/conf/residual/LayerNorm -> out ----------
  {
    const float* wg1 = Wg + lane * 8;
    const float* wg2 = Wg + DD + lane * 8;
    f32x4 g1a = *(const f32x4*)wg1, g1b = *(const f32x4*)(wg1 + 4);
    f32x4 g2a = *(const f32x4*)wg2, g2b = *(const f32x4*)(wg2 + 4);
    f32x4 la = *(const f32x4*)(lng + lane * 8), lb4 = *(const f32x4*)(lng + lane * 8 + 4);
    f32x4 ba = *(const f32x4*)(lnb + lane * 8), bb4 = *(const f32x4*)(lnb + lane * 8 + 4);
    const float bgs = bgp[0];
    for (int rr = 0; rr < 16; ++rr) {
      const int row = w * 16 + rr;
      const size_t b = (size_t)bm * 128 + row;
      const float* qp = q + b * DD + lane * 8;
      f32x4 q0 = *(const f32x4*)qp;
      f32x4 q1 = *(const f32x4*)(qp + 4);
      float qf[8] = {q0[0],q0[1],q0[2],q0[3],q1[0],q1[1],q1[2],q1[3]};
      const short8 mv = *(const short8*)&R1[row * DD + lane * 8];
      float mf[8];
#pragma unroll
      for (int i = 0; i < 8; ++i) mf[i] = bf2f(mv[i]);
      float gp = qf[0]*g1a[0]+qf[1]*g1a[1]+qf[2]*g1a[2]+qf[3]*g1a[3]
               + qf[4]*g1b[0]+qf[5]*g1b[1]+qf[6]*g1b[2]+qf[7]*g1b[3]
               + mf[0]*g2a[0]+mf[1]*g2a[1]+mf[2]*g2a[2]+mf[3]*g2a[3]
               + mf[4]*g2b[0]+mf[5]*g2b[1]+mf[6]*g2b[2]+mf[7]*g2b[3];
#pragma unroll
      for (int off = 32; off > 0; off >>= 1) gp += __shfl_xor(gp, off);
      const float gate = 1.f / (1.f + __expf(-(gp + bgs)));
      float ms = sims[b * KM];
#pragma unroll
      for (int k = 1; k < KM; ++k) ms = fmaxf(ms, sims[b * KM + k]);
      const float conf = 1.f / (1.f + __expf(-(ms - 0.7f)));
      const float gc = gate * conf;
      float o[8];
      float s1 = 0.f, s2 = 0.f;
#pragma unroll
      for (int i = 0; i < 8; ++i) {
        o[i] = qf[i] + gc * mf[i];
        s1 += o[i];
        s2 += o[i] * o[i];
      }
#pragma unroll
      for (int off = 32; off > 0; off >>= 1) { s1 += __shfl_xor(s1, off); s2 += __shfl_xor(s2, off); }
      const float mu = s1 * (1.f / 512.f);
      const float var = s2 * (1.f / 512.f) - mu * mu;
      const float rs = rsqrtf(var + 1e-5f);
      f32x4 r0, r1;
#pragma unroll
      for (int i = 0; i < 4; ++i) r0[i] = (o[i] - mu) * rs * la[i] + ba[i];
#pragma unroll
      for (int i = 0; i < 4; ++i) r1[i] = (o[4 + i] - mu) * rs * lb4[i] + bb4[i];
      float* op = outp + b * DD + lane * 8;
      __builtin_nontemporal_store(r0, (f32x4*)op);
      __builtin_nontemporal_store(r1, (f32x4*)(op + 4));
    }
  }
}

extern "C" void kernel_launch(void* const* d_in, const int* in_sizes, int n_in,
                              void* d_out, int out_size, void* d_ws, size_t ws_size,
                              hipStream_t stream) {
  const float* query = (const float*)d_in[0];
  const float* mem   = (const float*)d_in[1];
  const float* sims  = (const float*)d_in[2];
  const int*   mask  = (const int*)d_in[3];
  const float* Wq = (const float*)d_in[4];
  const float* bq = (const float*)d_in[5];
  const float* Wk = (const float*)d_in[6];
  // d_in[7] = bk: irrelevant (per-row constant on scores; softmax shift-invariant)
  const float* Wv = (const float*)d_in[8];
  const float* bv = (const float*)d_in[9];
  const float* Wo = (const float*)d_in[10];
  const float* bo = (const float*)d_in[11];
  const float* Wg = (const float*)d_in[12];
  const float* bg = (const float*)d_in[13];
  const float* ln_g = (const float*)d_in[14];
  const float* ln_b = (const float*)d_in[15];
  float* out = (float*)d_out;

  char* ws = (char*)d_ws;
  short* At = (short*)ws;                               // 512 KB  At[j][i] = (WqWk^T)[i][j] (n-major)
  short* Ct = At + (size_t)DD * DD;                     // 512 KB  Ct[j][d] = (WvWo)[d][j]
  float* w0 = (float*)(Ct + (size_t)DD * DD);           // 2 KB
  float* d0 = w0 + DD;                                  // 2 KB

  prep<<<dim3(2180), dim3(256), 0, stream>>>(Wq, bq, Wk, Wv, Wo, bo, bv, At, Ct, w0, d0);
  mk<<<dim3(B_ROWS / 128), dim3(512), 0, stream>>>(query, At, w0, mem, mask,
                                                   Ct, d0, sims, Wg, bg, ln_g, ln_b, out);
}